// Round 11
// baseline (881.026 us; speedup 1.0000x reference)
//
#include <hip/hip_runtime.h>
#include <hip/hip_bf16.h>
#include <cstddef>

// Problem constants
#define NB 256   // batch
#define RR 32    // rooms
#define WW 8     // room width
#define HH 6     // room height
#define MXY 72   // map extent
#define EMB 6
#define CIN1 16  // 9 + 1 + 6

typedef __bf16 bf16x8 __attribute__((ext_vector_type(8)));
typedef float floatx4 __attribute__((ext_vector_type(4)));

// --- Workspace layout (byte offsets) ---------------------------------------
// Conv weights packed per-kstep (2KB per kstep per ntile-group layout):
//   W1F: 13+1 ksteps [0,57344) ; W2F: 18 [57344,131072) ; W3F: 18 [131072,..)
static const size_t B_W1F  = 0;
static const size_t B_W2F  = 57344;
static const size_t B_W3F  = 131072;
static const size_t B_RAUX = 204800;    // room masks (32 u64)
static const size_t B_RINV = 205056;    // 1/room_size (32 f32)
static const size_t B_HEAD = 205312;    // fp32 head weights, 122880 floats
static const size_t F_WR1T = 0;         // (64,128)
static const size_t F_WR2T = 8192;      // (128,128)
static const size_t F_F1T  = 24576;     // (128,256)
static const size_t F_F2T  = 57344;     // (256,256)
static const size_t B_IMSK = 2793984;   // (256,32) u32 intersect masks (32 KB)
static const size_t B_SSUM = 2826752;   // (256,128) f32 room-sum accum (128 KB)
static const size_t B_CNT  = 2957824;   // (256) int done-counters (1 KB)

__device__ inline short f2b(float f) {
    unsigned u = __builtin_bit_cast(unsigned, f);
    unsigned r = (u + 0x7fffu + ((u >> 16) & 1u)) >> 16;
    return (short)r;
}

// ---------------------------------------------------------------------------
// ONE merged prep kernel. Disjoint index ranges:
//   [0, 225280)          weights -> bf16 B-frag order + head transposes
//   [225280, 233472)     per-(sample,room) 32-bit intersect masks
//   [233472, 233504)     room footprint bitmasks + 1/room_size
//   [233504, 266272)     zero SSUM (256x128 f32)
//   [266272, 266528)     zero CNT (256 int)
// Fragment order: [kk][ntile][lane][j] ; virtual k = kk*32 + (lane>>4)*8 + j
// oc = ntile*16 + (lane&15).
// conv1: (tap,ci) natural. conv2/3: position cp -> channel (cp>>2)+(cp&3)*16
// (paired-channel layout Y1/Y2 are written in).
// ---------------------------------------------------------------------------
__global__ void prep_all(const float* __restrict__ w1, const float* __restrict__ w2,
                         const float* __restrict__ w3, const float* __restrict__ wr1,
                         const float* __restrict__ wr2, const float* __restrict__ wf1,
                         const float* __restrict__ wf2, const float* __restrict__ rt,
                         const int* __restrict__ pos, char* __restrict__ ws)
{
    short* W1F = (short*)(ws + B_W1F);
    short* W2F = (short*)(ws + B_W2F);
    short* W3F = (short*)(ws + B_W3F);
    float* HEAD = (float*)(ws + B_HEAD);

    int idx = blockIdx.x * 256 + threadIdx.x;
    if (idx < 28672) {  // conv1: 14 ksteps (padded), CIN=16, taps 0..24 real
        int j = idx & 7, lane = (idx >> 3) & 63, nt = (idx >> 9) & 3, kk = idx >> 11;
        int k = kk * 32 + (lane >> 4) * 8 + j;
        int oc = nt * 16 + (lane & 15);
        int tap = k >> 4, ci = k & 15;
        float v = (tap < 25) ? w1[(oc * 16 + ci) * 25 + tap] : 0.f;
        W1F[idx] = f2b(v);
        return;
    }
    idx -= 28672;
    if (idx < 36864) {  // conv2: 18 ksteps, CIN=64, 9 taps, permuted ci
        int j = idx & 7, lane = (idx >> 3) & 63, nt = (idx >> 9) & 3, kk = idx >> 11;
        int k = kk * 32 + (lane >> 4) * 8 + j;
        int oc = nt * 16 + (lane & 15);
        int tap = k >> 6, cp = k & 63;
        int ci = (cp >> 2) + (cp & 3) * 16;
        W2F[idx] = f2b(w2[(oc * 64 + ci) * 9 + tap]);
        return;
    }
    idx -= 36864;
    if (idx < 36864) {  // conv3, permuted ci
        int j = idx & 7, lane = (idx >> 3) & 63, nt = (idx >> 9) & 3, kk = idx >> 11;
        int k = kk * 32 + (lane >> 4) * 8 + j;
        int oc = nt * 16 + (lane & 15);
        int tap = k >> 6, cp = k & 63;
        int ci = (cp >> 2) + (cp & 3) * 16;
        W3F[idx] = f2b(w3[(oc * 64 + ci) * 9 + tap]);
        return;
    }
    idx -= 36864;
    if (idx < 8192)  { int o = idx & 127, c = idx >> 7; HEAD[F_WR1T + idx] = wr1[o * 64 + c]; return; }
    idx -= 8192;
    if (idx < 16384) { int o = idx & 127, c = idx >> 7; HEAD[F_WR2T + idx] = wr2[o * 128 + c]; return; }
    idx -= 16384;
    if (idx < 32768) { int o = idx & 255, c = idx >> 8; HEAD[F_F1T + idx] = wf1[o * 128 + c]; return; }
    idx -= 32768;
    if (idx < 65536) { int o = idx & 255, c = idx >> 8; HEAD[F_F2T + idx] = wf2[o * 256 + c]; return; }
    idx -= 65536;
    if (idx < 8192) {  // intersect masks: rooms touching the 16x14 X halo tile
        const int n = idx >> 5, r0 = idx & 31;
        const int px0 = pos[(n * RR + r0) * 2 + 0];
        const int py0 = pos[(n * RR + r0) * 2 + 1];
        unsigned m = 0;
        for (int r = 0; r < RR; ++r) {
            int rpx = pos[(n * RR + r) * 2 + 0];
            int rpy = pos[(n * RR + r) * 2 + 1];
            if (rpx >= px0 - 11 && rpx <= px0 + 11 && rpy >= py0 - 9 && rpy <= py0 + 9)
                m |= 1u << r;
        }
        ((unsigned*)(ws + B_IMSK))[n * RR + r0] = m;
        return;
    }
    idx -= 8192;
    if (idx < RR) {  // room footprint bitmasks (48 bits) + 1/room_size
        unsigned long long m = 0ull;
        int cnt = 0;
        for (int j = 0; j < WW * HH; ++j)
            if (rt[idx * 9 * 48 + j] != 0.f) { m |= (1ull << j); ++cnt; }
        ((unsigned long long*)(ws + B_RAUX))[idx] = m;
        ((float*)(ws + B_RINV))[idx] = 1.f / (float)cnt;
        return;
    }
    idx -= RR;
    if (idx < NB * 128) { ((float*)(ws + B_SSUM))[idx] = 0.f; return; }  // zero SSUM
    idx -= NB * 128;
    if (idx < NB) ((int*)(ws + B_CNT))[idx] = 0;  // zero CNT
}

// ---------------------------------------------------------------------------
// ROUND-11 FULLY-FUSED KERNEL: conv chain + room-MLP + (last-block) fc head.
//
// Conv body == round-8/10's proven config (217.6us, spill-free (256,4)).
// New tail (runs in the conv's idle wave slots):
//  * room-MLP 64->128->128: block (room,n) owns the full 64-float room sum
//    in s_feat; 96 FMA + 96 coalesced L2 weight loads/thread; result
//    atomicAdd'ed into SSUM[n] (relaxed) -> head_rooms kernel + FEAT
//    round-trip deleted.
//  * last-block fc: __threadfence (release) then ACQ_REL fetch_add on
//    cnt[n]; the 32nd block for sample n reads SSUM[n] via agent-scope
//    atomic loads (bypass stale L1) and computes fc1+fc2 inline. Sample's
//    32 blocks are contiguous in dispatch order -> fc work spreads evenly.
// Pipeline is now TWO dispatches total.
// ---------------------------------------------------------------------------
__global__ __launch_bounds__(256, 4) void fused_all(
    const unsigned* __restrict__ imask, const float* __restrict__ rt,
    const float* __restrict__ emb, const short* __restrict__ wAll,
    const float* __restrict__ bc1, const float* __restrict__ bc2,
    const float* __restrict__ bc3, const int* __restrict__ pos,
    const unsigned long long* __restrict__ rmask, const float* __restrict__ HEAD,
    const float* __restrict__ rinv, const float* __restrict__ br1,
    const float* __restrict__ br2, const float* __restrict__ bf1,
    const float* __restrict__ bf2, float* __restrict__ ssum,
    int* __restrict__ cnt, float* __restrict__ outp)
{
    __shared__ __align__(16) short s_Y1[120 * 72];  // 17280 B, paired-channel
    __shared__ __align__(16) short s_u[80 * 72];    // X[224][24] then Y2[80][72]
    __shared__ float s_feat[64];
    __shared__ int s_last;

    const int tid = threadIdx.x;
    const int lane = tid & 63;
    const int wv = tid >> 6;
    const int ml = lane & 15;
    const int q = lane >> 4;
    const int room = blockIdx.x;
    const int n = blockIdx.y;

    const int px = pos[(n * RR + room) * 2 + 0];
    const int py = pos[(n * RR + room) * 2 + 1];

    const short* W1F = wAll;
    const short* W2F = wAll + B_W2F / 2;
    const short* W3F = wAll + B_W3F / 2;

    bf16x8 Bb[2][4];
    auto load_k = [&](const short* wF, int kk, bf16x8* dst) {
        const short* src = wF + (size_t)kk * 2048;
#pragma unroll
        for (int j2 = 0; j2 < 4; ++j2)
            dst[j2] = *reinterpret_cast<const bf16x8*>(src + (j2 * 64 + lane) * 8);
    };

    load_k(W1F, 0, Bb[0]);

    // ---- build X tile in-kernel: threads 0..223, one 16-channel pixel ----
    {
        const unsigned mk0 = imask[n * RR + room];  // uniform
        if (tid < 224) {
            const int row = tid / 14, col = tid - (tid / 14) * 14;
            const int gx = px - 4 + row, gy = py - 4 + col;
            float a[16];
#pragma unroll
            for (int c = 0; c < 16; ++c) a[c] = 0.f;
            a[9] = ((unsigned)gx < (unsigned)MXY && (unsigned)gy < (unsigned)MXY) ? 1.f : 0.f;

            unsigned mm = mk0;
            while (mm) {
                const int r = __builtin_ctz(mm);
                mm &= mm - 1;
                const int rpx = pos[(n * RR + r) * 2 + 0];  // uniform -> s_load
                const int rpy = pos[(n * RR + r) * 2 + 1];
                const int w = gx - rpx, h = gy - rpy;
                if ((unsigned)w < (unsigned)WW && (unsigned)h < (unsigned)HH) {
                    const int j = w * HH + h;
                    const float* rr = rt + r * 9 * 48;
#pragma unroll
                    for (int c = 0; c < 9; ++c) a[c] += rr[c * 48 + j];
                    const float mv = rr[j];  // channel 0 = room_map
#pragma unroll
                    for (int e = 0; e < EMB; ++e) a[10 + e] += emb[r * EMB + e] * mv;
                }
            }
            short o[16];
#pragma unroll
            for (int c = 0; c < 16; ++c) o[c] = f2b(a[c]);
            *reinterpret_cast<uint4*>(&s_u[tid * 24 + 0]) = *reinterpret_cast<uint4*>(o);
            *reinterpret_cast<uint4*>(&s_u[tid * 24 + 8]) = *reinterpret_cast<uint4*>(o + 8);
        }
    }
    __syncthreads();  // barrier 1: X staged

    // ================= conv1: 5x5, X(16ch) -> Y1 12x10x64 =================
    {
        int prow[2], pcol[2];
#pragma unroll
        for (int i = 0; i < 2; ++i) {
            int p = wv * 32 + i * 16 + ml;
            if (p > 119) p = 119;  // pad px: duplicate compute, discarded
            prow[i] = p / 10; pcol[i] = p - prow[i] * 10;
        }
        floatx4 acc1[2][4] = {};

#pragma unroll
        for (int kk = 0; kk < 13; ++kk) {  // taps 0..25 (25 zero-padded)
            if (kk < 12) load_k(W1F, kk + 1, Bb[(kk + 1) & 1]);
            else         load_k(W2F, 0, Bb[1]);  // chain prefetch into conv2
            int tap = kk * 2 + (q >> 1);
            if (tap > 24) tap = 24;  // k-slots past tap24 have zero weights
            int chb = (q & 1) * 8;
            int dx = tap / 5, dy = tap - dx * 5;
            __builtin_amdgcn_s_setprio(1);
#pragma unroll
            for (int i = 0; i < 2; ++i) {
                bf16x8 A = *reinterpret_cast<const bf16x8*>(
                    &s_u[((prow[i] + dx) * 14 + (pcol[i] + dy)) * 24 + chb]);
#pragma unroll
                for (int j2 = 0; j2 < 4; ++j2)
                    acc1[i][j2] = __builtin_amdgcn_mfma_f32_16x16x32_bf16(
                        A, Bb[kk & 1][j2], acc1[i][j2], 0, 0, 0);
            }
            __builtin_amdgcn_s_setprio(0);
        }
        // epilogue: bias + relu, b64 paired-channel stores
        float b4[4];
#pragma unroll
        for (int j2 = 0; j2 < 4; ++j2) b4[j2] = bc1[j2 * 16 + ml];
#pragma unroll
        for (int i = 0; i < 2; ++i)
#pragma unroll
            for (int r = 0; r < 4; ++r) {
                int p = wv * 32 + i * 16 + q * 4 + r;
                if (p < 120) {
                    unsigned lo = (unsigned)(unsigned short)f2b(fmaxf(acc1[i][0][r] + b4[0], 0.f))
                                | ((unsigned)(unsigned short)f2b(fmaxf(acc1[i][1][r] + b4[1], 0.f)) << 16);
                    unsigned hi = (unsigned)(unsigned short)f2b(fmaxf(acc1[i][2][r] + b4[2], 0.f))
                                | ((unsigned)(unsigned short)f2b(fmaxf(acc1[i][3][r] + b4[3], 0.f)) << 16);
                    *reinterpret_cast<uint2*>(&s_Y1[p * 72 + ml * 4]) = make_uint2(lo, hi);
                }
            }
    }
    __syncthreads();  // barrier 2: Y1 complete; X dead

    // ===== conv2: 3x3, Y1 -> Y2 10x8x64 (tiles 0-3 owned, tile 4 n-split) ==
    {
        int prowA, pcolA, prowB, pcolB;
        {
            int p0 = wv * 16 + ml; prowA = p0 >> 3; pcolA = p0 & 7;
            int p1 = 64 + ml;      prowB = p1 >> 3; pcolB = p1 & 7;
        }
        floatx4 acc2[4] = {};
        floatx4 acc2s = {};

#pragma unroll
        for (int kk = 0; kk < 18; ++kk) {
            if (kk < 17) load_k(W2F, kk + 1, Bb[kk & 1]);
            else         load_k(W3F, 0, Bb[1]);  // chain prefetch into conv3
            // n-split tile's B frag: direct per-kstep load (L1-resident),
            // wave-uniform base (rule #20 safe), no ping-pong liveness.
            bf16x8 B4 = *reinterpret_cast<const bf16x8*>(
                W2F + (size_t)kk * 2048 + (wv * 64 + lane) * 8);
            const int tap = kk >> 1;
            const int chb = (kk & 1) * 32 + q * 8;
            const int dx = tap / 3, dy = tap - (tap / 3) * 3;
            bf16x8 A0 = *reinterpret_cast<const bf16x8*>(
                &s_Y1[((prowA + dx) * 10 + (pcolA + dy)) * 72 + chb]);
            bf16x8 A4 = *reinterpret_cast<const bf16x8*>(
                &s_Y1[((prowB + dx) * 10 + (pcolB + dy)) * 72 + chb]);
            __builtin_amdgcn_s_setprio(1);
#pragma unroll
            for (int j2 = 0; j2 < 4; ++j2)
                acc2[j2] = __builtin_amdgcn_mfma_f32_16x16x32_bf16(A0, Bb[(kk + 1) & 1][j2], acc2[j2], 0, 0, 0);
            acc2s = __builtin_amdgcn_mfma_f32_16x16x32_bf16(A4, B4, acc2s, 0, 0, 0);
            __builtin_amdgcn_s_setprio(0);
        }
        // epilogue into s_u (X dead): own tile b64, shared tile scalar
        float b4[4];
#pragma unroll
        for (int j2 = 0; j2 < 4; ++j2) b4[j2] = bc2[j2 * 16 + ml];
#pragma unroll
        for (int r = 0; r < 4; ++r) {
            int p = wv * 16 + q * 4 + r;
            unsigned lo = (unsigned)(unsigned short)f2b(fmaxf(acc2[0][r] + b4[0], 0.f))
                        | ((unsigned)(unsigned short)f2b(fmaxf(acc2[1][r] + b4[1], 0.f)) << 16);
            unsigned hi = (unsigned)(unsigned short)f2b(fmaxf(acc2[2][r] + b4[2], 0.f))
                        | ((unsigned)(unsigned short)f2b(fmaxf(acc2[3][r] + b4[3], 0.f)) << 16);
            *reinterpret_cast<uint2*>(&s_u[p * 72 + ml * 4]) = make_uint2(lo, hi);
        }
        {
            float bt = bc2[wv * 16 + ml];
#pragma unroll
            for (int r = 0; r < 4; ++r) {
                int p = 64 + q * 4 + r;
                s_u[p * 72 + ml * 4 + wv] = f2b(fmaxf(acc2s[r] + bt, 0.f));
            }
        }
        if (tid < 64) s_feat[tid] = 0.f;
    }
    __syncthreads();  // barrier 3: Y2 complete

    // ====== conv3: 3x3, Y2 -> 8x6 masked room-sum (waves 0-2) ======
    if (wv < 3) {
        int p0 = wv * 16 + ml;
        int row3 = p0 / 6, col3 = p0 - (p0 / 6) * 6;
        floatx4 acc3[4] = {};

#pragma unroll
        for (int kk = 0; kk < 18; ++kk) {
            if (kk < 17) load_k(W3F, kk + 1, Bb[kk & 1]);
            const int tap = kk >> 1;
            const int chb = (kk & 1) * 32 + q * 8;
            const int dx = tap / 3, dy = tap - (tap / 3) * 3;
            bf16x8 A = *reinterpret_cast<const bf16x8*>(
                &s_u[((row3 + dx) * 8 + (col3 + dy)) * 72 + chb]);
            __builtin_amdgcn_s_setprio(1);
#pragma unroll
            for (int j2 = 0; j2 < 4; ++j2)
                acc3[j2] = __builtin_amdgcn_mfma_f32_16x16x32_bf16(A, Bb[(kk + 1) & 1][j2], acc3[j2], 0, 0, 0);
            __builtin_amdgcn_s_setprio(0);
        }
        float b4[4];
#pragma unroll
        for (int j2 = 0; j2 < 4; ++j2) b4[j2] = bc3[j2 * 16 + ml];
        float part[4] = {0.f, 0.f, 0.f, 0.f};
        const unsigned long long mk = rmask[room];
#pragma unroll
        for (int r = 0; r < 4; ++r) {
            int p = wv * 16 + q * 4 + r;  // == w*6+h == mask bit index
            if ((mk >> p) & 1ull) {
#pragma unroll
                for (int j2 = 0; j2 < 4; ++j2)
                    part[j2] += fmaxf(acc3[j2][r] + b4[j2], 0.f);
            }
        }
#pragma unroll
        for (int j2 = 0; j2 < 4; ++j2) {
            part[j2] += __shfl_xor(part[j2], 16);
            part[j2] += __shfl_xor(part[j2], 32);
        }
        if (q == 0) {
#pragma unroll
            for (int j2 = 0; j2 < 4; ++j2)
                atomicAdd(&s_feat[j2 * 16 + ml], part[j2]);  // 3 contenders
        }
    }
    __syncthreads();  // barrier 4: s_feat = 64 unnormalized room-channel sums

    // ====== room-MLP 64->128->128 in-block; accumulate into SSUM[n] ======
    {
        float* s_ps = (float*)s_u;          // 256 f32 partials (s_u free)
        float* s_h1 = (float*)s_Y1;         // 128 f32 h1 / later sf (s_Y1 free)
        const int o = tid & 127;
        const int rh = tid >> 7;
        const float rv = rinv[room];
        const float* W1t = HEAD + F_WR1T;
        const float* W2t = HEAD + F_WR2T;

        // h1 partials: c in [rh*32, rh*32+32)
        float a = 0.f;
#pragma unroll
        for (int c4 = 0; c4 < 8; ++c4) {
            float4 f = *reinterpret_cast<const float4*>(&s_feat[rh * 32 + c4 * 4]);
            a += f.x * W1t[(rh * 32 + c4 * 4 + 0) * 128 + o];
            a += f.y * W1t[(rh * 32 + c4 * 4 + 1) * 128 + o];
            a += f.z * W1t[(rh * 32 + c4 * 4 + 2) * 128 + o];
            a += f.w * W1t[(rh * 32 + c4 * 4 + 3) * 128 + o];
        }
        s_ps[tid] = a;
        __syncthreads();
        if (tid < 128)
            s_h1[tid] = fmaxf(br1[tid] + rv * (s_ps[tid] + s_ps[128 + tid]), 0.f);
        __syncthreads();

        // h2 partials: c in [rh*64, rh*64+64)
        a = 0.f;
#pragma unroll
        for (int c4 = 0; c4 < 16; ++c4) {
            float4 f = *reinterpret_cast<const float4*>(&s_h1[rh * 64 + c4 * 4]);
            a += f.x * W2t[(rh * 64 + c4 * 4 + 0) * 128 + o];
            a += f.y * W2t[(rh * 64 + c4 * 4 + 1) * 128 + o];
            a += f.z * W2t[(rh * 64 + c4 * 4 + 2) * 128 + o];
            a += f.w * W2t[(rh * 64 + c4 * 4 + 3) * 128 + o];
        }
        s_ps[tid] = a;
        __syncthreads();
        if (tid < 128) {
            float p = fmaxf(br2[tid] + s_ps[tid] + s_ps[128 + tid], 0.f);
            atomicAdd(&ssum[(size_t)n * 128 + tid], p);
        }
    }

    // ====== last-block-done: the 32nd block for sample n runs fc1+fc2 ======
    __threadfence();  // release our SSUM adds before signaling
    if (tid == 0) {
        int prev = __hip_atomic_fetch_add(&cnt[n], 1, __ATOMIC_ACQ_REL,
                                          __HIP_MEMORY_SCOPE_AGENT);
        s_last = (prev == RR - 1);
    }
    __syncthreads();
    if (!s_last) return;

    {
        float* s_sf = (float*)s_Y1;          // 128 f32 (h1 dead)
        float* s_t1 = (float*)s_u;           // 256 f32 (partials dead)
        const float* F1t = HEAD + F_F1T;
        const float* F2t = HEAD + F_F2T;

        if (tid < 128)
            s_sf[tid] = __hip_atomic_load(&ssum[(size_t)n * 128 + tid],
                                          __ATOMIC_RELAXED, __HIP_MEMORY_SCOPE_AGENT);
        __syncthreads();

        float a = bf1[tid];
#pragma unroll 4
        for (int c4 = 0; c4 < 32; ++c4) {
            float4 f = *reinterpret_cast<const float4*>(&s_sf[c4 * 4]);
            a += f.x * F1t[(c4 * 4 + 0) * 256 + tid];
            a += f.y * F1t[(c4 * 4 + 1) * 256 + tid];
            a += f.z * F1t[(c4 * 4 + 2) * 256 + tid];
            a += f.w * F1t[(c4 * 4 + 3) * 256 + tid];
        }
        s_t1[tid] = fmaxf(a, 0.f);
        __syncthreads();

        a = bf2[tid];
#pragma unroll 4
        for (int c4 = 0; c4 < 64; ++c4) {
            float4 f = *reinterpret_cast<const float4*>(&s_t1[c4 * 4]);
            a += f.x * F2t[(c4 * 4 + 0) * 256 + tid];
            a += f.y * F2t[(c4 * 4 + 1) * 256 + tid];
            a += f.z * F2t[(c4 * 4 + 2) * 256 + tid];
            a += f.w * F2t[(c4 * 4 + 3) * 256 + tid];
        }
        outp[(size_t)n * 256 + tid] = a;
    }
}

// ---------------------------------------------------------------------------
extern "C" void kernel_launch(void* const* d_in, const int* in_sizes, int n_in,
                              void* d_out, int out_size, void* d_ws, size_t ws_size,
                              hipStream_t stream)
{
    const int* pos = (const int*)d_in[0];
    const float* rt = (const float*)d_in[1];
    const float* emb = (const float*)d_in[2];
    const float* w1 = (const float*)d_in[3];
    const float* bc1 = (const float*)d_in[4];
    const float* w2 = (const float*)d_in[5];
    const float* bc2 = (const float*)d_in[6];
    const float* w3 = (const float*)d_in[7];
    const float* bc3 = (const float*)d_in[8];
    const float* wr1 = (const float*)d_in[9];
    const float* br1 = (const float*)d_in[10];
    const float* wr2 = (const float*)d_in[11];
    const float* br2 = (const float*)d_in[12];
    const float* wf1 = (const float*)d_in[13];
    const float* bf1 = (const float*)d_in[14];
    const float* wf2 = (const float*)d_in[15];
    const float* bf2 = (const float*)d_in[16];
    float* out = (float*)d_out;
    char* ws = (char*)d_ws;

    // merged prep: 225280 weight + 8192 imask + 32 room + 32768 ssum + 256 cnt
    prep_all<<<1042, 256, 0, stream>>>(w1, w2, w3, wr1, wr2, wf1, wf2, rt, pos, ws);

    const short* WALL = (const short*)(ws + B_W1F);
    const unsigned long long* RMASK = (const unsigned long long*)(ws + B_RAUX);
    const float* RINV = (const float*)(ws + B_RINV);
    const float* HEAD = (const float*)(ws + B_HEAD);
    unsigned* IMSK = (unsigned*)(ws + B_IMSK);
    float* SSUM = (float*)(ws + B_SSUM);
    int* CNT = (int*)(ws + B_CNT);

    fused_all<<<dim3(RR, NB), 256, 0, stream>>>(IMSK, rt, emb, WALL,
                                                bc1, bc2, bc3, pos, RMASK, HEAD,
                                                RINV, br1, br2, bf1, bf2,
                                                SSUM, CNT, out);
}

// Round 12
// 314.325 us; speedup vs baseline: 2.8029x; 2.8029x over previous
//
#include <hip/hip_runtime.h>
#include <hip/hip_bf16.h>
#include <cstddef>

// Problem constants
#define NB 256   // batch
#define RR 32    // rooms
#define WW 8     // room width
#define HH 6     // room height
#define MXY 72   // map extent
#define EMB 6
#define CIN1 16  // 9 + 1 + 6

typedef __bf16 bf16x8 __attribute__((ext_vector_type(8)));
typedef float floatx4 __attribute__((ext_vector_type(4)));

// --- Workspace layout (byte offsets) ---------------------------------------
// Conv weights packed per-kstep (2KB per kstep per ntile-group layout):
//   W1F: 13+1 ksteps [0,57344) ; W2F: 18 [57344,131072) ; W3F: 18 [131072,..)
static const size_t B_W1F  = 0;
static const size_t B_W2F  = 57344;
static const size_t B_W3F  = 131072;
static const size_t B_RAUX = 204800;    // room masks (32 u64)
static const size_t B_RINV = 205056;    // 1/room_size (32 f32)
static const size_t B_HEAD = 205312;    // fp32 head weights, 122880 floats
static const size_t F_WR1T = 0;         // (64,128)
static const size_t F_WR2T = 8192;      // (128,128)
static const size_t F_F1T  = 24576;     // (128,256)
static const size_t F_F2T  = 57344;     // (256,256)
static const size_t B_IMSK = 2793984;   // (256,32) u32 intersect masks (32 KB)
static const size_t B_SSUM = 2826752;   // (256,128) f32 room-sum accum (128 KB)

__device__ inline short f2b(float f) {
    unsigned u = __builtin_bit_cast(unsigned, f);
    unsigned r = (u + 0x7fffu + ((u >> 16) & 1u)) >> 16;
    return (short)r;
}

// ---------------------------------------------------------------------------
// ONE merged prep kernel. Disjoint index ranges:
//   [0, 225280)          weights -> bf16 B-frag order + head transposes
//   [225280, 233472)     per-(sample,room) 32-bit intersect masks
//   [233472, 233504)     room footprint bitmasks + 1/room_size
//   [233504, 266272)     zero SSUM (256x128 f32)
// Fragment order: [kk][ntile][lane][j] ; virtual k = kk*32 + (lane>>4)*8 + j
// oc = ntile*16 + (lane&15).
// conv1: (tap,ci) natural. conv2/3: position cp -> channel (cp>>2)+(cp&3)*16
// (paired-channel layout Y1/Y2 are written in).
// ---------------------------------------------------------------------------
__global__ void prep_all(const float* __restrict__ w1, const float* __restrict__ w2,
                         const float* __restrict__ w3, const float* __restrict__ wr1,
                         const float* __restrict__ wr2, const float* __restrict__ wf1,
                         const float* __restrict__ wf2, const float* __restrict__ rt,
                         const int* __restrict__ pos, char* __restrict__ ws)
{
    short* W1F = (short*)(ws + B_W1F);
    short* W2F = (short*)(ws + B_W2F);
    short* W3F = (short*)(ws + B_W3F);
    float* HEAD = (float*)(ws + B_HEAD);

    int idx = blockIdx.x * 256 + threadIdx.x;
    if (idx < 28672) {  // conv1: 14 ksteps (padded), CIN=16, taps 0..24 real
        int j = idx & 7, lane = (idx >> 3) & 63, nt = (idx >> 9) & 3, kk = idx >> 11;
        int k = kk * 32 + (lane >> 4) * 8 + j;
        int oc = nt * 16 + (lane & 15);
        int tap = k >> 4, ci = k & 15;
        float v = (tap < 25) ? w1[(oc * 16 + ci) * 25 + tap] : 0.f;
        W1F[idx] = f2b(v);
        return;
    }
    idx -= 28672;
    if (idx < 36864) {  // conv2: 18 ksteps, CIN=64, 9 taps, permuted ci
        int j = idx & 7, lane = (idx >> 3) & 63, nt = (idx >> 9) & 3, kk = idx >> 11;
        int k = kk * 32 + (lane >> 4) * 8 + j;
        int oc = nt * 16 + (lane & 15);
        int tap = k >> 6, cp = k & 63;
        int ci = (cp >> 2) + (cp & 3) * 16;
        W2F[idx] = f2b(w2[(oc * 64 + ci) * 9 + tap]);
        return;
    }
    idx -= 36864;
    if (idx < 36864) {  // conv3, permuted ci
        int j = idx & 7, lane = (idx >> 3) & 63, nt = (idx >> 9) & 3, kk = idx >> 11;
        int k = kk * 32 + (lane >> 4) * 8 + j;
        int oc = nt * 16 + (lane & 15);
        int tap = k >> 6, cp = k & 63;
        int ci = (cp >> 2) + (cp & 3) * 16;
        W3F[idx] = f2b(w3[(oc * 64 + ci) * 9 + tap]);
        return;
    }
    idx -= 36864;
    if (idx < 8192)  { int o = idx & 127, c = idx >> 7; HEAD[F_WR1T + idx] = wr1[o * 64 + c]; return; }
    idx -= 8192;
    if (idx < 16384) { int o = idx & 127, c = idx >> 7; HEAD[F_WR2T + idx] = wr2[o * 128 + c]; return; }
    idx -= 16384;
    if (idx < 32768) { int o = idx & 255, c = idx >> 8; HEAD[F_F1T + idx] = wf1[o * 128 + c]; return; }
    idx -= 32768;
    if (idx < 65536) { int o = idx & 255, c = idx >> 8; HEAD[F_F2T + idx] = wf2[o * 256 + c]; return; }
    idx -= 65536;
    if (idx < 8192) {  // intersect masks: rooms touching the 16x14 X halo tile
        const int n = idx >> 5, r0 = idx & 31;
        const int px0 = pos[(n * RR + r0) * 2 + 0];
        const int py0 = pos[(n * RR + r0) * 2 + 1];
        unsigned m = 0;
        for (int r = 0; r < RR; ++r) {
            int rpx = pos[(n * RR + r) * 2 + 0];
            int rpy = pos[(n * RR + r) * 2 + 1];
            if (rpx >= px0 - 11 && rpx <= px0 + 11 && rpy >= py0 - 9 && rpy <= py0 + 9)
                m |= 1u << r;
        }
        ((unsigned*)(ws + B_IMSK))[n * RR + r0] = m;
        return;
    }
    idx -= 8192;
    if (idx < RR) {  // room footprint bitmasks (48 bits) + 1/room_size
        unsigned long long m = 0ull;
        int cnt = 0;
        for (int j = 0; j < WW * HH; ++j)
            if (rt[idx * 9 * 48 + j] != 0.f) { m |= (1ull << j); ++cnt; }
        ((unsigned long long*)(ws + B_RAUX))[idx] = m;
        ((float*)(ws + B_RINV))[idx] = 1.f / (float)cnt;
        return;
    }
    idx -= RR;
    if (idx < NB * 128) ((float*)(ws + B_SSUM))[idx] = 0.f;  // zero SSUM
}

// ---------------------------------------------------------------------------
// ROUND-12 FUSED CONV + ROOM-MLP (round-11 minus the fences).
//
// Round-11 post-mortem: 842us (4x regression) with MfmaUtil scaled by the
// same factor = uniform stall. The per-block __threadfence + ACQ_REL
// agent-scope RMW compile to L2 writeback/invalidate cache-maintenance ops
// on the non-coherent 8-XCD design; 8192 of them serialize at the fabric
// (~75ns each ~= the whole 600us regression). Round 10's head_rooms did the
// SAME SSUM atomicAdds with no fences and was fast -> keep the room-MLP
// fusion + plain atomicAdd, drop the last-block fc (separate head_fc kernel
// with natural dispatch-boundary ordering instead).
//
// Conv body == round-8/10's proven config (217.6us, spill-free (256,4)).
// ---------------------------------------------------------------------------
__global__ __launch_bounds__(256, 4) void fused_all(
    const unsigned* __restrict__ imask, const float* __restrict__ rt,
    const float* __restrict__ emb, const short* __restrict__ wAll,
    const float* __restrict__ bc1, const float* __restrict__ bc2,
    const float* __restrict__ bc3, const int* __restrict__ pos,
    const unsigned long long* __restrict__ rmask, const float* __restrict__ HEAD,
    const float* __restrict__ rinv, const float* __restrict__ br1,
    const float* __restrict__ br2, float* __restrict__ ssum)
{
    __shared__ __align__(16) short s_Y1[120 * 72];  // 17280 B, paired-channel
    __shared__ __align__(16) short s_u[80 * 72];    // X[224][24] then Y2[80][72]
    __shared__ float s_feat[64];

    const int tid = threadIdx.x;
    const int lane = tid & 63;
    const int wv = tid >> 6;
    const int ml = lane & 15;
    const int q = lane >> 4;
    const int room = blockIdx.x;
    const int n = blockIdx.y;

    const int px = pos[(n * RR + room) * 2 + 0];
    const int py = pos[(n * RR + room) * 2 + 1];

    const short* W1F = wAll;
    const short* W2F = wAll + B_W2F / 2;
    const short* W3F = wAll + B_W3F / 2;

    bf16x8 Bb[2][4];
    auto load_k = [&](const short* wF, int kk, bf16x8* dst) {
        const short* src = wF + (size_t)kk * 2048;
#pragma unroll
        for (int j2 = 0; j2 < 4; ++j2)
            dst[j2] = *reinterpret_cast<const bf16x8*>(src + (j2 * 64 + lane) * 8);
    };

    load_k(W1F, 0, Bb[0]);

    // ---- build X tile in-kernel: threads 0..223, one 16-channel pixel ----
    {
        const unsigned mk0 = imask[n * RR + room];  // uniform
        if (tid < 224) {
            const int row = tid / 14, col = tid - (tid / 14) * 14;
            const int gx = px - 4 + row, gy = py - 4 + col;
            float a[16];
#pragma unroll
            for (int c = 0; c < 16; ++c) a[c] = 0.f;
            a[9] = ((unsigned)gx < (unsigned)MXY && (unsigned)gy < (unsigned)MXY) ? 1.f : 0.f;

            unsigned mm = mk0;
            while (mm) {
                const int r = __builtin_ctz(mm);
                mm &= mm - 1;
                const int rpx = pos[(n * RR + r) * 2 + 0];  // uniform -> s_load
                const int rpy = pos[(n * RR + r) * 2 + 1];
                const int w = gx - rpx, h = gy - rpy;
                if ((unsigned)w < (unsigned)WW && (unsigned)h < (unsigned)HH) {
                    const int j = w * HH + h;
                    const float* rr = rt + r * 9 * 48;
#pragma unroll
                    for (int c = 0; c < 9; ++c) a[c] += rr[c * 48 + j];
                    const float mv = rr[j];  // channel 0 = room_map
#pragma unroll
                    for (int e = 0; e < EMB; ++e) a[10 + e] += emb[r * EMB + e] * mv;
                }
            }
            short o[16];
#pragma unroll
            for (int c = 0; c < 16; ++c) o[c] = f2b(a[c]);
            *reinterpret_cast<uint4*>(&s_u[tid * 24 + 0]) = *reinterpret_cast<uint4*>(o);
            *reinterpret_cast<uint4*>(&s_u[tid * 24 + 8]) = *reinterpret_cast<uint4*>(o + 8);
        }
    }
    __syncthreads();  // barrier 1: X staged

    // ================= conv1: 5x5, X(16ch) -> Y1 12x10x64 =================
    {
        int prow[2], pcol[2];
#pragma unroll
        for (int i = 0; i < 2; ++i) {
            int p = wv * 32 + i * 16 + ml;
            if (p > 119) p = 119;  // pad px: duplicate compute, discarded
            prow[i] = p / 10; pcol[i] = p - prow[i] * 10;
        }
        floatx4 acc1[2][4] = {};

#pragma unroll
        for (int kk = 0; kk < 13; ++kk) {  // taps 0..25 (25 zero-padded)
            if (kk < 12) load_k(W1F, kk + 1, Bb[(kk + 1) & 1]);
            else         load_k(W2F, 0, Bb[1]);  // chain prefetch into conv2
            int tap = kk * 2 + (q >> 1);
            if (tap > 24) tap = 24;  // k-slots past tap24 have zero weights
            int chb = (q & 1) * 8;
            int dx = tap / 5, dy = tap - dx * 5;
            __builtin_amdgcn_s_setprio(1);
#pragma unroll
            for (int i = 0; i < 2; ++i) {
                bf16x8 A = *reinterpret_cast<const bf16x8*>(
                    &s_u[((prow[i] + dx) * 14 + (pcol[i] + dy)) * 24 + chb]);
#pragma unroll
                for (int j2 = 0; j2 < 4; ++j2)
                    acc1[i][j2] = __builtin_amdgcn_mfma_f32_16x16x32_bf16(
                        A, Bb[kk & 1][j2], acc1[i][j2], 0, 0, 0);
            }
            __builtin_amdgcn_s_setprio(0);
        }
        // epilogue: bias + relu, b64 paired-channel stores
        float b4[4];
#pragma unroll
        for (int j2 = 0; j2 < 4; ++j2) b4[j2] = bc1[j2 * 16 + ml];
#pragma unroll
        for (int i = 0; i < 2; ++i)
#pragma unroll
            for (int r = 0; r < 4; ++r) {
                int p = wv * 32 + i * 16 + q * 4 + r;
                if (p < 120) {
                    unsigned lo = (unsigned)(unsigned short)f2b(fmaxf(acc1[i][0][r] + b4[0], 0.f))
                                | ((unsigned)(unsigned short)f2b(fmaxf(acc1[i][1][r] + b4[1], 0.f)) << 16);
                    unsigned hi = (unsigned)(unsigned short)f2b(fmaxf(acc1[i][2][r] + b4[2], 0.f))
                                | ((unsigned)(unsigned short)f2b(fmaxf(acc1[i][3][r] + b4[3], 0.f)) << 16);
                    *reinterpret_cast<uint2*>(&s_Y1[p * 72 + ml * 4]) = make_uint2(lo, hi);
                }
            }
    }
    __syncthreads();  // barrier 2: Y1 complete; X dead

    // ===== conv2: 3x3, Y1 -> Y2 10x8x64 (tiles 0-3 owned, tile 4 n-split) ==
    {
        int prowA, pcolA, prowB, pcolB;
        {
            int p0 = wv * 16 + ml; prowA = p0 >> 3; pcolA = p0 & 7;
            int p1 = 64 + ml;      prowB = p1 >> 3; pcolB = p1 & 7;
        }
        floatx4 acc2[4] = {};
        floatx4 acc2s = {};

#pragma unroll
        for (int kk = 0; kk < 18; ++kk) {
            if (kk < 17) load_k(W2F, kk + 1, Bb[kk & 1]);
            else         load_k(W3F, 0, Bb[1]);  // chain prefetch into conv3
            // n-split tile's B frag: direct per-kstep load (L1-resident),
            // wave-uniform base (rule #20 safe), no ping-pong liveness.
            bf16x8 B4 = *reinterpret_cast<const bf16x8*>(
                W2F + (size_t)kk * 2048 + (wv * 64 + lane) * 8);
            const int tap = kk >> 1;
            const int chb = (kk & 1) * 32 + q * 8;
            const int dx = tap / 3, dy = tap - (tap / 3) * 3;
            bf16x8 A0 = *reinterpret_cast<const bf16x8*>(
                &s_Y1[((prowA + dx) * 10 + (pcolA + dy)) * 72 + chb]);
            bf16x8 A4 = *reinterpret_cast<const bf16x8*>(
                &s_Y1[((prowB + dx) * 10 + (pcolB + dy)) * 72 + chb]);
            __builtin_amdgcn_s_setprio(1);
#pragma unroll
            for (int j2 = 0; j2 < 4; ++j2)
                acc2[j2] = __builtin_amdgcn_mfma_f32_16x16x32_bf16(A0, Bb[(kk + 1) & 1][j2], acc2[j2], 0, 0, 0);
            acc2s = __builtin_amdgcn_mfma_f32_16x16x32_bf16(A4, B4, acc2s, 0, 0, 0);
            __builtin_amdgcn_s_setprio(0);
        }
        // epilogue into s_u (X dead): own tile b64, shared tile scalar
        float b4[4];
#pragma unroll
        for (int j2 = 0; j2 < 4; ++j2) b4[j2] = bc2[j2 * 16 + ml];
#pragma unroll
        for (int r = 0; r < 4; ++r) {
            int p = wv * 16 + q * 4 + r;
            unsigned lo = (unsigned)(unsigned short)f2b(fmaxf(acc2[0][r] + b4[0], 0.f))
                        | ((unsigned)(unsigned short)f2b(fmaxf(acc2[1][r] + b4[1], 0.f)) << 16);
            unsigned hi = (unsigned)(unsigned short)f2b(fmaxf(acc2[2][r] + b4[2], 0.f))
                        | ((unsigned)(unsigned short)f2b(fmaxf(acc2[3][r] + b4[3], 0.f)) << 16);
            *reinterpret_cast<uint2*>(&s_u[p * 72 + ml * 4]) = make_uint2(lo, hi);
        }
        {
            float bt = bc2[wv * 16 + ml];
#pragma unroll
            for (int r = 0; r < 4; ++r) {
                int p = 64 + q * 4 + r;
                s_u[p * 72 + ml * 4 + wv] = f2b(fmaxf(acc2s[r] + bt, 0.f));
            }
        }
        if (tid < 64) s_feat[tid] = 0.f;
    }
    __syncthreads();  // barrier 3: Y2 complete

    // ====== conv3: 3x3, Y2 -> 8x6 masked room-sum (waves 0-2) ======
    if (wv < 3) {
        int p0 = wv * 16 + ml;
        int row3 = p0 / 6, col3 = p0 - (p0 / 6) * 6;
        floatx4 acc3[4] = {};

#pragma unroll
        for (int kk = 0; kk < 18; ++kk) {
            if (kk < 17) load_k(W3F, kk + 1, Bb[kk & 1]);
            const int tap = kk >> 1;
            const int chb = (kk & 1) * 32 + q * 8;
            const int dx = tap / 3, dy = tap - (tap / 3) * 3;
            bf16x8 A = *reinterpret_cast<const bf16x8*>(
                &s_u[((row3 + dx) * 8 + (col3 + dy)) * 72 + chb]);
            __builtin_amdgcn_s_setprio(1);
#pragma unroll
            for (int j2 = 0; j2 < 4; ++j2)
                acc3[j2] = __builtin_amdgcn_mfma_f32_16x16x32_bf16(A, Bb[(kk + 1) & 1][j2], acc3[j2], 0, 0, 0);
            __builtin_amdgcn_s_setprio(0);
        }
        float b4[4];
#pragma unroll
        for (int j2 = 0; j2 < 4; ++j2) b4[j2] = bc3[j2 * 16 + ml];
        float part[4] = {0.f, 0.f, 0.f, 0.f};
        const unsigned long long mk = rmask[room];
#pragma unroll
        for (int r = 0; r < 4; ++r) {
            int p = wv * 16 + q * 4 + r;  // == w*6+h == mask bit index
            if ((mk >> p) & 1ull) {
#pragma unroll
                for (int j2 = 0; j2 < 4; ++j2)
                    part[j2] += fmaxf(acc3[j2][r] + b4[j2], 0.f);
            }
        }
#pragma unroll
        for (int j2 = 0; j2 < 4; ++j2) {
            part[j2] += __shfl_xor(part[j2], 16);
            part[j2] += __shfl_xor(part[j2], 32);
        }
        if (q == 0) {
#pragma unroll
            for (int j2 = 0; j2 < 4; ++j2)
                atomicAdd(&s_feat[j2 * 16 + ml], part[j2]);  // 3 contenders
        }
    }
    __syncthreads();  // barrier 4: s_feat = 64 unnormalized room-channel sums

    // ====== room-MLP 64->128->128 in-block; accumulate into SSUM[n] ======
    // Plain device-scope atomicAdd only — NO threadfence / acquire RMW
    // (round-11 lesson: per-block cache-maintenance ops cost ~600us).
    {
        float* s_ps = (float*)s_u;          // 256 f32 partials (s_u free)
        float* s_h1 = (float*)s_Y1;         // 128 f32 h1 (s_Y1 free)
        const int o = tid & 127;
        const int rh = tid >> 7;
        const float rv = rinv[room];
        const float* W1t = HEAD + F_WR1T;
        const float* W2t = HEAD + F_WR2T;

        // h1 partials: c in [rh*32, rh*32+32)
        float a = 0.f;
#pragma unroll
        for (int c4 = 0; c4 < 8; ++c4) {
            float4 f = *reinterpret_cast<const float4*>(&s_feat[rh * 32 + c4 * 4]);
            a += f.x * W1t[(rh * 32 + c4 * 4 + 0) * 128 + o];
            a += f.y * W1t[(rh * 32 + c4 * 4 + 1) * 128 + o];
            a += f.z * W1t[(rh * 32 + c4 * 4 + 2) * 128 + o];
            a += f.w * W1t[(rh * 32 + c4 * 4 + 3) * 128 + o];
        }
        s_ps[tid] = a;
        __syncthreads();
        if (tid < 128)
            s_h1[tid] = fmaxf(br1[tid] + rv * (s_ps[tid] + s_ps[128 + tid]), 0.f);
        __syncthreads();

        // h2 partials: c in [rh*64, rh*64+64)
        a = 0.f;
#pragma unroll
        for (int c4 = 0; c4 < 16; ++c4) {
            float4 f = *reinterpret_cast<const float4*>(&s_h1[rh * 64 + c4 * 4]);
            a += f.x * W2t[(rh * 64 + c4 * 4 + 0) * 128 + o];
            a += f.y * W2t[(rh * 64 + c4 * 4 + 1) * 128 + o];
            a += f.z * W2t[(rh * 64 + c4 * 4 + 2) * 128 + o];
            a += f.w * W2t[(rh * 64 + c4 * 4 + 3) * 128 + o];
        }
        s_ps[tid] = a;
        __syncthreads();
        if (tid < 128) {
            float p = fmaxf(br2[tid] + s_ps[tid] + s_ps[128 + tid], 0.f);
            atomicAdd(&ssum[(size_t)n * 128 + tid], p);
        }
    }
}

// ---------------------------------------------------------------------------
// fc1 (128->256) + fc2 (256->256) per sample, from SSUM. Separate dispatch:
// the kernel boundary provides the ordering round 11 tried (and failed) to
// get from per-block fences.
// ---------------------------------------------------------------------------
__global__ __launch_bounds__(256) void head_fc(const float* __restrict__ ssum,
                                               const float* __restrict__ HEAD,
                                               const float* __restrict__ bf1,
                                               const float* __restrict__ bf2,
                                               float* __restrict__ outp)
{
    __shared__ __align__(16) float s_sf[128];
    __shared__ __align__(16) float s_t1[256];

    const int n = blockIdx.x;
    const int tid = threadIdx.x;
    const float* F1t = HEAD + F_F1T;
    const float* F2t = HEAD + F_F2T;

    if (tid < 128) s_sf[tid] = ssum[(size_t)n * 128 + tid];
    __syncthreads();

    {
        float a = bf1[tid];
#pragma unroll 4
        for (int c4 = 0; c4 < 32; ++c4) {
            float4 f = *reinterpret_cast<const float4*>(&s_sf[c4 * 4]);
            a += f.x * F1t[(c4 * 4 + 0) * 256 + tid];
            a += f.y * F1t[(c4 * 4 + 1) * 256 + tid];
            a += f.z * F1t[(c4 * 4 + 2) * 256 + tid];
            a += f.w * F1t[(c4 * 4 + 3) * 256 + tid];
        }
        s_t1[tid] = fmaxf(a, 0.f);
    }
    __syncthreads();

    {
        float a = bf2[tid];
#pragma unroll 4
        for (int c4 = 0; c4 < 64; ++c4) {
            float4 f = *reinterpret_cast<const float4*>(&s_t1[c4 * 4]);
            a += f.x * F2t[(c4 * 4 + 0) * 256 + tid];
            a += f.y * F2t[(c4 * 4 + 1) * 256 + tid];
            a += f.z * F2t[(c4 * 4 + 2) * 256 + tid];
            a += f.w * F2t[(c4 * 4 + 3) * 256 + tid];
        }
        outp[(size_t)n * 256 + tid] = a;
    }
}

// ---------------------------------------------------------------------------
extern "C" void kernel_launch(void* const* d_in, const int* in_sizes, int n_in,
                              void* d_out, int out_size, void* d_ws, size_t ws_size,
                              hipStream_t stream)
{
    const int* pos = (const int*)d_in[0];
    const float* rt = (const float*)d_in[1];
    const float* emb = (const float*)d_in[2];
    const float* w1 = (const float*)d_in[3];
    const float* bc1 = (const float*)d_in[4];
    const float* w2 = (const float*)d_in[5];
    const float* bc2 = (const float*)d_in[6];
    const float* w3 = (const float*)d_in[7];
    const float* bc3 = (const float*)d_in[8];
    const float* wr1 = (const float*)d_in[9];
    const float* br1 = (const float*)d_in[10];
    const float* wr2 = (const float*)d_in[11];
    const float* br2 = (const float*)d_in[12];
    const float* wf1 = (const float*)d_in[13];
    const float* bf1 = (const float*)d_in[14];
    const float* wf2 = (const float*)d_in[15];
    const float* bf2 = (const float*)d_in[16];
    float* out = (float*)d_out;
    char* ws = (char*)d_ws;

    // merged prep: 225280 weight + 8192 imask + 32 room + 32768 ssum-zero ids
    prep_all<<<1041, 256, 0, stream>>>(w1, w2, w3, wr1, wr2, wf1, wf2, rt, pos, ws);

    const short* WALL = (const short*)(ws + B_W1F);
    const unsigned long long* RMASK = (const unsigned long long*)(ws + B_RAUX);
    const float* RINV = (const float*)(ws + B_RINV);
    const float* HEAD = (const float*)(ws + B_HEAD);
    unsigned* IMSK = (unsigned*)(ws + B_IMSK);
    float* SSUM = (float*)(ws + B_SSUM);

    fused_all<<<dim3(RR, NB), 256, 0, stream>>>(IMSK, rt, emb, WALL,
                                                bc1, bc2, bc3, pos, RMASK, HEAD,
                                                RINV, br1, br2, SSUM);

    head_fc<<<NB, 256, 0, stream>>>(SSUM, HEAD, bf1, bf2, out);
}

// Round 13
// 300.744 us; speedup vs baseline: 2.9295x; 1.0452x over previous
//
#include <hip/hip_runtime.h>
#include <hip/hip_bf16.h>
#include <cstddef>

// Problem constants
#define NB 256   // batch
#define RR 32    // rooms
#define WW 8     // room width
#define HH 6     // room height
#define MXY 72   // map extent
#define EMB 6
#define CIN1 16  // 9 + 1 + 6

typedef __bf16 bf16x8 __attribute__((ext_vector_type(8)));
typedef float floatx4 __attribute__((ext_vector_type(4)));

// --- Workspace layout (byte offsets) ---------------------------------------
// Conv weights packed per-kstep (2KB per kstep per ntile-group layout):
//   W1F: 13+1 ksteps [0,57344) ; W2F: 18 [57344,131072) ; W3F: 18 [131072,..)
static const size_t B_W1F  = 0;
static const size_t B_W2F  = 57344;
static const size_t B_W3F  = 131072;
static const size_t B_RAUX = 204800;    // room masks (32 u64)
static const size_t B_RINV = 205056;    // 1/room_size (32 f32)
static const size_t B_HEAD = 205312;    // fp32 head weights, 122880 floats
static const size_t F_WR1T = 0;         // (64,128)
static const size_t F_WR2T = 8192;      // (128,128)
static const size_t F_F1T  = 24576;     // (128,256)
static const size_t F_F2T  = 57344;     // (256,256)
static const size_t B_FEAT = 696832;    // (256,32,64) f32 = 2 MB
static const size_t B_IMSK = 2793984;   // (256,32) u32 intersect masks (32 KB)
static const size_t B_SSUM = 2826752;   // (256,4,128) f32 partial slots (512 KB)

__device__ inline short f2b(float f) {
    unsigned u = __builtin_bit_cast(unsigned, f);
    unsigned r = (u + 0x7fffu + ((u >> 16) & 1u)) >> 16;
    return (short)r;
}

// ---------------------------------------------------------------------------
// ONE merged prep kernel. Disjoint index ranges:
//   [0, 225280)          weights -> bf16 B-frag order + head transposes
//   [225280, 233472)     per-(sample,room) 32-bit intersect masks
//   [233472, 233504)     room footprint bitmasks + 1/room_size
// (SSUM no longer zeroed: head_rooms writes every slot unconditionally.)
// Fragment order: [kk][ntile][lane][j] ; virtual k = kk*32 + (lane>>4)*8 + j
// oc = ntile*16 + (lane&15).
// conv1: (tap,ci) natural. conv2/3: position cp -> channel (cp>>2)+(cp&3)*16
// (paired-channel layout Y1/Y2 are written in).
// ---------------------------------------------------------------------------
__global__ void prep_all(const float* __restrict__ w1, const float* __restrict__ w2,
                         const float* __restrict__ w3, const float* __restrict__ wr1,
                         const float* __restrict__ wr2, const float* __restrict__ wf1,
                         const float* __restrict__ wf2, const float* __restrict__ rt,
                         const int* __restrict__ pos, char* __restrict__ ws)
{
    short* W1F = (short*)(ws + B_W1F);
    short* W2F = (short*)(ws + B_W2F);
    short* W3F = (short*)(ws + B_W3F);
    float* HEAD = (float*)(ws + B_HEAD);

    int idx = blockIdx.x * 256 + threadIdx.x;
    if (idx < 28672) {  // conv1: 14 ksteps (padded), CIN=16, taps 0..24 real
        int j = idx & 7, lane = (idx >> 3) & 63, nt = (idx >> 9) & 3, kk = idx >> 11;
        int k = kk * 32 + (lane >> 4) * 8 + j;
        int oc = nt * 16 + (lane & 15);
        int tap = k >> 4, ci = k & 15;
        float v = (tap < 25) ? w1[(oc * 16 + ci) * 25 + tap] : 0.f;
        W1F[idx] = f2b(v);
        return;
    }
    idx -= 28672;
    if (idx < 36864) {  // conv2: 18 ksteps, CIN=64, 9 taps, permuted ci
        int j = idx & 7, lane = (idx >> 3) & 63, nt = (idx >> 9) & 3, kk = idx >> 11;
        int k = kk * 32 + (lane >> 4) * 8 + j;
        int oc = nt * 16 + (lane & 15);
        int tap = k >> 6, cp = k & 63;
        int ci = (cp >> 2) + (cp & 3) * 16;
        W2F[idx] = f2b(w2[(oc * 64 + ci) * 9 + tap]);
        return;
    }
    idx -= 36864;
    if (idx < 36864) {  // conv3, permuted ci
        int j = idx & 7, lane = (idx >> 3) & 63, nt = (idx >> 9) & 3, kk = idx >> 11;
        int k = kk * 32 + (lane >> 4) * 8 + j;
        int oc = nt * 16 + (lane & 15);
        int tap = k >> 6, cp = k & 63;
        int ci = (cp >> 2) + (cp & 3) * 16;
        W3F[idx] = f2b(w3[(oc * 64 + ci) * 9 + tap]);
        return;
    }
    idx -= 36864;
    if (idx < 8192)  { int o = idx & 127, c = idx >> 7; HEAD[F_WR1T + idx] = wr1[o * 64 + c]; return; }
    idx -= 8192;
    if (idx < 16384) { int o = idx & 127, c = idx >> 7; HEAD[F_WR2T + idx] = wr2[o * 128 + c]; return; }
    idx -= 16384;
    if (idx < 32768) { int o = idx & 255, c = idx >> 8; HEAD[F_F1T + idx] = wf1[o * 128 + c]; return; }
    idx -= 32768;
    if (idx < 65536) { int o = idx & 255, c = idx >> 8; HEAD[F_F2T + idx] = wf2[o * 256 + c]; return; }
    idx -= 65536;
    if (idx < 8192) {  // intersect masks: rooms touching the 16x14 X halo tile
        const int n = idx >> 5, r0 = idx & 31;
        const int px0 = pos[(n * RR + r0) * 2 + 0];
        const int py0 = pos[(n * RR + r0) * 2 + 1];
        unsigned m = 0;
        for (int r = 0; r < RR; ++r) {
            int rpx = pos[(n * RR + r) * 2 + 0];
            int rpy = pos[(n * RR + r) * 2 + 1];
            if (rpx >= px0 - 11 && rpx <= px0 + 11 && rpy >= py0 - 9 && rpy <= py0 + 9)
                m |= 1u << r;
        }
        ((unsigned*)(ws + B_IMSK))[n * RR + r0] = m;
        return;
    }
    idx -= 8192;
    if (idx < RR) {  // room footprint bitmasks (48 bits) + 1/room_size
        unsigned long long m = 0ull;
        int cnt = 0;
        for (int j = 0; j < WW * HH; ++j)
            if (rt[idx * 9 * 48 + j] != 0.f) { m |= (1ull << j); ++cnt; }
        ((unsigned long long*)(ws + B_RAUX))[idx] = m;
        ((float*)(ws + B_RINV))[idx] = 1.f / (float)cnt;
    }
}

// ---------------------------------------------------------------------------
// FUSED CONV CHAIN == round-8/10's proven config (217.6us, spill-free
// (256,4)). Final form after 8 structural probes (rounds 0-12):
//  * per-(room,sample) block; X gathered in-kernel from the ~4-room
//    intersect mask (no global X buffer);
//  * conv1->conv2->conv3 chained entirely in LDS (Y1/Y2 never in HBM);
//  * B frags in registers from global (L1 dedups across waves — LDS-staged
//    B made the LDS pipe the wall, rounds 4/5);
//  * (256,4): spill-free; (256,5) spills (r6/r9), 2-blk convoy slower (r5);
//  * conv3 output reduced in-register to the 64-float masked room sum.
// Fusing the room-MLP here regressed (r12: 8x head-weight L2 traffic);
// per-block fences catastrophically regressed (r11: cache-maintenance ops).
// ---------------------------------------------------------------------------
__global__ __launch_bounds__(256, 4) void fused_conv(
    const unsigned* __restrict__ imask, const float* __restrict__ rt,
    const float* __restrict__ emb, const short* __restrict__ wAll,
    const float* __restrict__ bc1, const float* __restrict__ bc2,
    const float* __restrict__ bc3, const int* __restrict__ pos,
    const unsigned long long* __restrict__ rmask, float* __restrict__ feat)
{
    __shared__ __align__(16) short s_Y1[120 * 72];  // 17280 B, paired-channel
    __shared__ __align__(16) short s_u[80 * 72];    // X[224][24] then Y2[80][72]
    __shared__ float s_feat[64];

    const int tid = threadIdx.x;
    const int lane = tid & 63;
    const int wv = tid >> 6;
    const int ml = lane & 15;
    const int q = lane >> 4;
    const int room = blockIdx.x;
    const int n = blockIdx.y;

    const int px = pos[(n * RR + room) * 2 + 0];
    const int py = pos[(n * RR + room) * 2 + 1];

    const short* W1F = wAll;
    const short* W2F = wAll + B_W2F / 2;
    const short* W3F = wAll + B_W3F / 2;

    bf16x8 Bb[2][4];
    auto load_k = [&](const short* wF, int kk, bf16x8* dst) {
        const short* src = wF + (size_t)kk * 2048;
#pragma unroll
        for (int j2 = 0; j2 < 4; ++j2)
            dst[j2] = *reinterpret_cast<const bf16x8*>(src + (j2 * 64 + lane) * 8);
    };

    load_k(W1F, 0, Bb[0]);

    // ---- build X tile in-kernel: threads 0..223, one 16-channel pixel ----
    {
        const unsigned mk0 = imask[n * RR + room];  // uniform
        if (tid < 224) {
            const int row = tid / 14, col = tid - (tid / 14) * 14;
            const int gx = px - 4 + row, gy = py - 4 + col;
            float a[16];
#pragma unroll
            for (int c = 0; c < 16; ++c) a[c] = 0.f;
            a[9] = ((unsigned)gx < (unsigned)MXY && (unsigned)gy < (unsigned)MXY) ? 1.f : 0.f;

            unsigned mm = mk0;
            while (mm) {
                const int r = __builtin_ctz(mm);
                mm &= mm - 1;
                const int rpx = pos[(n * RR + r) * 2 + 0];  // uniform -> s_load
                const int rpy = pos[(n * RR + r) * 2 + 1];
                const int w = gx - rpx, h = gy - rpy;
                if ((unsigned)w < (unsigned)WW && (unsigned)h < (unsigned)HH) {
                    const int j = w * HH + h;
                    const float* rr = rt + r * 9 * 48;
#pragma unroll
                    for (int c = 0; c < 9; ++c) a[c] += rr[c * 48 + j];
                    const float mv = rr[j];  // channel 0 = room_map
#pragma unroll
                    for (int e = 0; e < EMB; ++e) a[10 + e] += emb[r * EMB + e] * mv;
                }
            }
            short o[16];
#pragma unroll
            for (int c = 0; c < 16; ++c) o[c] = f2b(a[c]);
            *reinterpret_cast<uint4*>(&s_u[tid * 24 + 0]) = *reinterpret_cast<uint4*>(o);
            *reinterpret_cast<uint4*>(&s_u[tid * 24 + 8]) = *reinterpret_cast<uint4*>(o + 8);
        }
    }
    __syncthreads();  // barrier 1: X staged

    // ================= conv1: 5x5, X(16ch) -> Y1 12x10x64 =================
    {
        int prow[2], pcol[2];
#pragma unroll
        for (int i = 0; i < 2; ++i) {
            int p = wv * 32 + i * 16 + ml;
            if (p > 119) p = 119;  // pad px: duplicate compute, discarded
            prow[i] = p / 10; pcol[i] = p - prow[i] * 10;
        }
        floatx4 acc1[2][4] = {};

#pragma unroll
        for (int kk = 0; kk < 13; ++kk) {  // taps 0..25 (25 zero-padded)
            if (kk < 12) load_k(W1F, kk + 1, Bb[(kk + 1) & 1]);
            else         load_k(W2F, 0, Bb[1]);  // chain prefetch into conv2
            int tap = kk * 2 + (q >> 1);
            if (tap > 24) tap = 24;  // k-slots past tap24 have zero weights
            int chb = (q & 1) * 8;
            int dx = tap / 5, dy = tap - dx * 5;
            __builtin_amdgcn_s_setprio(1);
#pragma unroll
            for (int i = 0; i < 2; ++i) {
                bf16x8 A = *reinterpret_cast<const bf16x8*>(
                    &s_u[((prow[i] + dx) * 14 + (pcol[i] + dy)) * 24 + chb]);
#pragma unroll
                for (int j2 = 0; j2 < 4; ++j2)
                    acc1[i][j2] = __builtin_amdgcn_mfma_f32_16x16x32_bf16(
                        A, Bb[kk & 1][j2], acc1[i][j2], 0, 0, 0);
            }
            __builtin_amdgcn_s_setprio(0);
        }
        // epilogue: bias + relu, b64 paired-channel stores
        float b4[4];
#pragma unroll
        for (int j2 = 0; j2 < 4; ++j2) b4[j2] = bc1[j2 * 16 + ml];
#pragma unroll
        for (int i = 0; i < 2; ++i)
#pragma unroll
            for (int r = 0; r < 4; ++r) {
                int p = wv * 32 + i * 16 + q * 4 + r;
                if (p < 120) {
                    unsigned lo = (unsigned)(unsigned short)f2b(fmaxf(acc1[i][0][r] + b4[0], 0.f))
                                | ((unsigned)(unsigned short)f2b(fmaxf(acc1[i][1][r] + b4[1], 0.f)) << 16);
                    unsigned hi = (unsigned)(unsigned short)f2b(fmaxf(acc1[i][2][r] + b4[2], 0.f))
                                | ((unsigned)(unsigned short)f2b(fmaxf(acc1[i][3][r] + b4[3], 0.f)) << 16);
                    *reinterpret_cast<uint2*>(&s_Y1[p * 72 + ml * 4]) = make_uint2(lo, hi);
                }
            }
    }
    __syncthreads();  // barrier 2: Y1 complete; X dead

    // ===== conv2: 3x3, Y1 -> Y2 10x8x64 (tiles 0-3 owned, tile 4 n-split) ==
    {
        int prowA, pcolA, prowB, pcolB;
        {
            int p0 = wv * 16 + ml; prowA = p0 >> 3; pcolA = p0 & 7;
            int p1 = 64 + ml;      prowB = p1 >> 3; pcolB = p1 & 7;
        }
        floatx4 acc2[4] = {};
        floatx4 acc2s = {};

#pragma unroll
        for (int kk = 0; kk < 18; ++kk) {
            if (kk < 17) load_k(W2F, kk + 1, Bb[kk & 1]);
            else         load_k(W3F, 0, Bb[1]);  // chain prefetch into conv3
            // n-split tile's B frag: direct per-kstep load (L1-resident),
            // wave-uniform base (rule #20 safe), no ping-pong liveness.
            bf16x8 B4 = *reinterpret_cast<const bf16x8*>(
                W2F + (size_t)kk * 2048 + (wv * 64 + lane) * 8);
            const int tap = kk >> 1;
            const int chb = (kk & 1) * 32 + q * 8;
            const int dx = tap / 3, dy = tap - (tap / 3) * 3;
            bf16x8 A0 = *reinterpret_cast<const bf16x8*>(
                &s_Y1[((prowA + dx) * 10 + (pcolA + dy)) * 72 + chb]);
            bf16x8 A4 = *reinterpret_cast<const bf16x8*>(
                &s_Y1[((prowB + dx) * 10 + (pcolB + dy)) * 72 + chb]);
            __builtin_amdgcn_s_setprio(1);
#pragma unroll
            for (int j2 = 0; j2 < 4; ++j2)
                acc2[j2] = __builtin_amdgcn_mfma_f32_16x16x32_bf16(A0, Bb[(kk + 1) & 1][j2], acc2[j2], 0, 0, 0);
            acc2s = __builtin_amdgcn_mfma_f32_16x16x32_bf16(A4, B4, acc2s, 0, 0, 0);
            __builtin_amdgcn_s_setprio(0);
        }
        // epilogue into s_u (X dead): own tile b64, shared tile scalar
        float b4[4];
#pragma unroll
        for (int j2 = 0; j2 < 4; ++j2) b4[j2] = bc2[j2 * 16 + ml];
#pragma unroll
        for (int r = 0; r < 4; ++r) {
            int p = wv * 16 + q * 4 + r;
            unsigned lo = (unsigned)(unsigned short)f2b(fmaxf(acc2[0][r] + b4[0], 0.f))
                        | ((unsigned)(unsigned short)f2b(fmaxf(acc2[1][r] + b4[1], 0.f)) << 16);
            unsigned hi = (unsigned)(unsigned short)f2b(fmaxf(acc2[2][r] + b4[2], 0.f))
                        | ((unsigned)(unsigned short)f2b(fmaxf(acc2[3][r] + b4[3], 0.f)) << 16);
            *reinterpret_cast<uint2*>(&s_u[p * 72 + ml * 4]) = make_uint2(lo, hi);
        }
        {
            float bt = bc2[wv * 16 + ml];
#pragma unroll
            for (int r = 0; r < 4; ++r) {
                int p = 64 + q * 4 + r;
                s_u[p * 72 + ml * 4 + wv] = f2b(fmaxf(acc2s[r] + bt, 0.f));
            }
        }
        if (tid < 64) s_feat[tid] = 0.f;
    }
    __syncthreads();  // barrier 3: Y2 complete

    // ====== conv3: 3x3, Y2 -> 8x6 masked room-sum (waves 0-2) ======
    if (wv < 3) {
        int p0 = wv * 16 + ml;
        int row3 = p0 / 6, col3 = p0 - (p0 / 6) * 6;
        floatx4 acc3[4] = {};

#pragma unroll
        for (int kk = 0; kk < 18; ++kk) {
            if (kk < 17) load_k(W3F, kk + 1, Bb[kk & 1]);
            const int tap = kk >> 1;
            const int chb = (kk & 1) * 32 + q * 8;
            const int dx = tap / 3, dy = tap - (tap / 3) * 3;
            bf16x8 A = *reinterpret_cast<const bf16x8*>(
                &s_u[((row3 + dx) * 8 + (col3 + dy)) * 72 + chb]);
            __builtin_amdgcn_s_setprio(1);
#pragma unroll
            for (int j2 = 0; j2 < 4; ++j2)
                acc3[j2] = __builtin_amdgcn_mfma_f32_16x16x32_bf16(A, Bb[(kk + 1) & 1][j2], acc3[j2], 0, 0, 0);
            __builtin_amdgcn_s_setprio(0);
        }
        float b4[4];
#pragma unroll
        for (int j2 = 0; j2 < 4; ++j2) b4[j2] = bc3[j2 * 16 + ml];
        float part[4] = {0.f, 0.f, 0.f, 0.f};
        const unsigned long long mk = rmask[room];
#pragma unroll
        for (int r = 0; r < 4; ++r) {
            int p = wv * 16 + q * 4 + r;  // == w*6+h == mask bit index
            if ((mk >> p) & 1ull) {
#pragma unroll
                for (int j2 = 0; j2 < 4; ++j2)
                    part[j2] += fmaxf(acc3[j2][r] + b4[j2], 0.f);
            }
        }
#pragma unroll
        for (int j2 = 0; j2 < 4; ++j2) {
            part[j2] += __shfl_xor(part[j2], 16);
            part[j2] += __shfl_xor(part[j2], 32);
        }
        if (q == 0) {
#pragma unroll
            for (int j2 = 0; j2 < 4; ++j2)
                atomicAdd(&s_feat[j2 * 16 + ml], part[j2]);  // 3 contenders
        }
    }
    __syncthreads();  // barrier 4
    if (tid < 64)
        feat[((size_t)n * RR + room) * 64 + tid] = s_feat[tid];
}

// ---------------------------------------------------------------------------
// Head split (round-10 structure, proven): head_rooms = 4 blocks/sample,
// 8 rooms each (amortizes the 96KB head-weight read over 8 rooms — the
// fused variant at 1 room/block was L2-BW-bound, round 12). Partial
// room-sums go to PRIVATE slots (no atomics, no zero pass); head_fc sums 4.
// ---------------------------------------------------------------------------
__global__ __launch_bounds__(256) void head_rooms(const float* __restrict__ feat,
                                                  const float* __restrict__ HEAD,
                                                  const float* __restrict__ rinv,
                                                  const float* __restrict__ b1,
                                                  const float* __restrict__ b2,
                                                  float* __restrict__ ssum)
{
    __shared__ __align__(16) float s_feat[8 * 64];
    __shared__ __align__(16) float s_h1[8 * 128];
    __shared__ __align__(16) float s_s[2 * 128];

    const int qr = blockIdx.x;   // 0..3 -> rooms qr*8 .. qr*8+7
    const int n = blockIdx.y;
    const int tid = threadIdx.x;
    const float* W1t = HEAD + F_WR1T;
    const float* W2t = HEAD + F_WR2T;

    for (int i = tid; i < 8 * 64; i += 256)
        s_feat[i] = feat[(size_t)n * RR * 64 + qr * 512 + i] * rinv[qr * 8 + (i >> 6)];
    __syncthreads();

    const int o = tid & 127;
    const int rh = tid >> 7;     // rooms rh*4 .. rh*4+3 (local)

    float acc[4];
#pragma unroll
    for (int r = 0; r < 4; ++r) acc[r] = b1[o];
    for (int c4 = 0; c4 < 16; ++c4) {
        float w0 = W1t[(c4 * 4 + 0) * 128 + o];
        float w1 = W1t[(c4 * 4 + 1) * 128 + o];
        float w2 = W1t[(c4 * 4 + 2) * 128 + o];
        float w3 = W1t[(c4 * 4 + 3) * 128 + o];
#pragma unroll
        for (int r = 0; r < 4; ++r) {
            float4 f = *reinterpret_cast<const float4*>(&s_feat[(rh * 4 + r) * 64 + c4 * 4]);
            acc[r] += f.x * w0 + f.y * w1 + f.z * w2 + f.w * w3;
        }
    }
#pragma unroll
    for (int r = 0; r < 4; ++r) s_h1[(rh * 4 + r) * 128 + o] = fmaxf(acc[r], 0.f);
    __syncthreads();

#pragma unroll
    for (int r = 0; r < 4; ++r) acc[r] = b2[o];
    for (int c4 = 0; c4 < 32; ++c4) {
        float w0 = W2t[(c4 * 4 + 0) * 128 + o];
        float w1 = W2t[(c4 * 4 + 1) * 128 + o];
        float w2 = W2t[(c4 * 4 + 2) * 128 + o];
        float w3 = W2t[(c4 * 4 + 3) * 128 + o];
#pragma unroll
        for (int r = 0; r < 4; ++r) {
            float4 f = *reinterpret_cast<const float4*>(&s_h1[(rh * 4 + r) * 128 + c4 * 4]);
            acc[r] += f.x * w0 + f.y * w1 + f.z * w2 + f.w * w3;
        }
    }
    float ps = 0.f;
#pragma unroll
    for (int r = 0; r < 4; ++r) ps += fmaxf(acc[r], 0.f);
    s_s[rh * 128 + o] = ps;
    __syncthreads();
    if (tid < 128)
        ssum[((size_t)n * 4 + qr) * 128 + tid] = s_s[tid] + s_s[128 + tid];
}

__global__ __launch_bounds__(256) void head_fc(const float* __restrict__ ssum,
                                               const float* __restrict__ HEAD,
                                               const float* __restrict__ bf1,
                                               const float* __restrict__ bf2,
                                               float* __restrict__ outp)
{
    __shared__ __align__(16) float s_sf[128];
    __shared__ __align__(16) float s_t1[256];

    const int n = blockIdx.x;
    const int tid = threadIdx.x;
    const float* F1t = HEAD + F_F1T;
    const float* F2t = HEAD + F_F2T;

    if (tid < 128) {
        const float* s0 = ssum + (size_t)n * 4 * 128 + tid;
        s_sf[tid] = (s0[0] + s0[128]) + (s0[256] + s0[384]);
    }
    __syncthreads();

    {
        float a = bf1[tid];
#pragma unroll 4
        for (int c4 = 0; c4 < 32; ++c4) {
            float4 f = *reinterpret_cast<const float4*>(&s_sf[c4 * 4]);
            a += f.x * F1t[(c4 * 4 + 0) * 256 + tid];
            a += f.y * F1t[(c4 * 4 + 1) * 256 + tid];
            a += f.z * F1t[(c4 * 4 + 2) * 256 + tid];
            a += f.w * F1t[(c4 * 4 + 3) * 256 + tid];
        }
        s_t1[tid] = fmaxf(a, 0.f);
    }
    __syncthreads();

    {
        float a = bf2[tid];
#pragma unroll 4
        for (int c4 = 0; c4 < 64; ++c4) {
            float4 f = *reinterpret_cast<const float4*>(&s_t1[c4 * 4]);
            a += f.x * F2t[(c4 * 4 + 0) * 256 + tid];
            a += f.y * F2t[(c4 * 4 + 1) * 256 + tid];
            a += f.z * F2t[(c4 * 4 + 2) * 256 + tid];
            a += f.w * F2t[(c4 * 4 + 3) * 256 + tid];
        }
        outp[(size_t)n * 256 + tid] = a;
    }
}

// ---------------------------------------------------------------------------
extern "C" void kernel_launch(void* const* d_in, const int* in_sizes, int n_in,
                              void* d_out, int out_size, void* d_ws, size_t ws_size,
                              hipStream_t stream)
{
    const int* pos = (const int*)d_in[0];
    const float* rt = (const float*)d_in[1];
    const float* emb = (const float*)d_in[2];
    const float* w1 = (const float*)d_in[3];
    const float* bc1 = (const float*)d_in[4];
    const float* w2 = (const float*)d_in[5];
    const float* bc2 = (const float*)d_in[6];
    const float* w3 = (const float*)d_in[7];
    const float* bc3 = (const float*)d_in[8];
    const float* wr1 = (const float*)d_in[9];
    const float* br1 = (const float*)d_in[10];
    const float* wr2 = (const float*)d_in[11];
    const float* br2 = (const float*)d_in[12];
    const float* wf1 = (const float*)d_in[13];
    const float* bf1 = (const float*)d_in[14];
    const float* wf2 = (const float*)d_in[15];
    const float* bf2 = (const float*)d_in[16];
    float* out = (float*)d_out;
    char* ws = (char*)d_ws;

    // merged prep: 225280 weight + 8192 imask + 32 room ids
    prep_all<<<913, 256, 0, stream>>>(w1, w2, w3, wr1, wr2, wf1, wf2, rt, pos, ws);

    const short* WALL = (const short*)(ws + B_W1F);
    const unsigned long long* RMASK = (const unsigned long long*)(ws + B_RAUX);
    const float* RINV = (const float*)(ws + B_RINV);
    const float* HEAD = (const float*)(ws + B_HEAD);
    float* FEAT = (float*)(ws + B_FEAT);
    unsigned* IMSK = (unsigned*)(ws + B_IMSK);
    float* SSUM = (float*)(ws + B_SSUM);

    fused_conv<<<dim3(RR, NB), 256, 0, stream>>>(IMSK, rt, emb, WALL,
                                                 bc1, bc2, bc3, pos, RMASK, FEAT);

    head_rooms<<<dim3(4, NB), 256, 0, stream>>>(FEAT, HEAD, RINV, br1, br2, SSUM);
    head_fc<<<NB, 256, 0, stream>>>(SSUM, HEAD, bf1, bf2, out);
}

// Round 14
// 277.148 us; speedup vs baseline: 3.1789x; 1.0851x over previous
//
#include <hip/hip_runtime.h>
#include <hip/hip_bf16.h>
#include <cstddef>

// Problem constants
#define NB 256   // batch
#define RR 32    // rooms
#define WW 8     // room width
#define HH 6     // room height
#define MXY 72   // map extent
#define EMB 6
#define CIN1 16  // 9 + 1 + 6

typedef __bf16 bf16x8 __attribute__((ext_vector_type(8)));
typedef float floatx4 __attribute__((ext_vector_type(4)));

// --- Workspace layout (byte offsets) ---------------------------------------
// Conv weights packed as 25 contiguous 8KB phases (2 ksteps each):
//   W1F: 7 phases [0,57344) ; W2F: 9 [57344,131072) ; W3F: 9 [131072,204800)
static const size_t B_W1F  = 0;
static const size_t B_W2F  = 57344;
static const size_t B_W3F  = 131072;
static const size_t B_RAUX = 204800;    // room masks (32 u64)
static const size_t B_RINV = 205056;    // 1/room_size (32 f32)
static const size_t B_HEAD = 205312;    // fp32 head weights, 122880 floats
static const size_t F_WR1T = 0;         // (64,128)
static const size_t F_WR2T = 8192;      // (128,128)
static const size_t F_F1T  = 24576;     // (128,256)
static const size_t F_F2T  = 57344;     // (256,256)
static const size_t B_FEAT = 696832;    // (256,32,64) f32 = 2 MB
static const size_t B_IMSK = 2793984;   // (256,32) u32 intersect masks (32 KB)
static const size_t B_SSUM = 2826752;   // (256,4,128) f32 partial slots (512 KB)

__device__ inline short f2b(float f) {
    unsigned u = __builtin_bit_cast(unsigned, f);
    unsigned r = (u + 0x7fffu + ((u >> 16) & 1u)) >> 16;
    return (short)r;
}

// ---------------------------------------------------------------------------
// ONE merged prep kernel. Disjoint index ranges:
//   [0, 225280)          weights -> bf16 B-frag order + head transposes
//   [225280, 233472)     per-(sample,room) 32-bit intersect masks
//   [233472, 233504)     room footprint bitmasks + 1/room_size
// Fragment order: [kk][ntile][lane][j] ; virtual k = kk*32 + (lane>>4)*8 + j
// oc = ntile*16 + (lane&15).
// conv1: (tap,ci) natural. conv2/3: position cp -> channel (cp>>2)+(cp&3)*16
// (paired-channel layout Y1/Y2 are written in).
// ---------------------------------------------------------------------------
__global__ void prep_all(const float* __restrict__ w1, const float* __restrict__ w2,
                         const float* __restrict__ w3, const float* __restrict__ wr1,
                         const float* __restrict__ wr2, const float* __restrict__ wf1,
                         const float* __restrict__ wf2, const float* __restrict__ rt,
                         const int* __restrict__ pos, char* __restrict__ ws)
{
    short* W1F = (short*)(ws + B_W1F);
    short* W2F = (short*)(ws + B_W2F);
    short* W3F = (short*)(ws + B_W3F);
    float* HEAD = (float*)(ws + B_HEAD);

    int idx = blockIdx.x * 256 + threadIdx.x;
    if (idx < 28672) {  // conv1: 14 ksteps (padded), CIN=16, taps 0..24 real
        int j = idx & 7, lane = (idx >> 3) & 63, nt = (idx >> 9) & 3, kk = idx >> 11;
        int k = kk * 32 + (lane >> 4) * 8 + j;
        int oc = nt * 16 + (lane & 15);
        int tap = k >> 4, ci = k & 15;
        float v = (tap < 25) ? w1[(oc * 16 + ci) * 25 + tap] : 0.f;
        W1F[idx] = f2b(v);
        return;
    }
    idx -= 28672;
    if (idx < 36864) {  // conv2: 18 ksteps, CIN=64, 9 taps, permuted ci
        int j = idx & 7, lane = (idx >> 3) & 63, nt = (idx >> 9) & 3, kk = idx >> 11;
        int k = kk * 32 + (lane >> 4) * 8 + j;
        int oc = nt * 16 + (lane & 15);
        int tap = k >> 6, cp = k & 63;
        int ci = (cp >> 2) + (cp & 3) * 16;
        W2F[idx] = f2b(w2[(oc * 64 + ci) * 9 + tap]);
        return;
    }
    idx -= 36864;
    if (idx < 36864) {  // conv3, permuted ci
        int j = idx & 7, lane = (idx >> 3) & 63, nt = (idx >> 9) & 3, kk = idx >> 11;
        int k = kk * 32 + (lane >> 4) * 8 + j;
        int oc = nt * 16 + (lane & 15);
        int tap = k >> 6, cp = k & 63;
        int ci = (cp >> 2) + (cp & 3) * 16;
        W3F[idx] = f2b(w3[(oc * 64 + ci) * 9 + tap]);
        return;
    }
    idx -= 36864;
    if (idx < 8192)  { int o = idx & 127, c = idx >> 7; HEAD[F_WR1T + idx] = wr1[o * 64 + c]; return; }
    idx -= 8192;
    if (idx < 16384) { int o = idx & 127, c = idx >> 7; HEAD[F_WR2T + idx] = wr2[o * 128 + c]; return; }
    idx -= 16384;
    if (idx < 32768) { int o = idx & 255, c = idx >> 8; HEAD[F_F1T + idx] = wf1[o * 128 + c]; return; }
    idx -= 32768;
    if (idx < 65536) { int o = idx & 255, c = idx >> 8; HEAD[F_F2T + idx] = wf2[o * 256 + c]; return; }
    idx -= 65536;
    if (idx < 8192) {  // intersect masks: rooms touching the 16x14 X halo tile
        const int n = idx >> 5, r0 = idx & 31;
        const int px0 = pos[(n * RR + r0) * 2 + 0];
        const int py0 = pos[(n * RR + r0) * 2 + 1];
        unsigned m = 0;
        for (int r = 0; r < RR; ++r) {
            int rpx = pos[(n * RR + r) * 2 + 0];
            int rpy = pos[(n * RR + r) * 2 + 1];
            if (rpx >= px0 - 11 && rpx <= px0 + 11 && rpy >= py0 - 9 && rpy <= py0 + 9)
                m |= 1u << r;
        }
        ((unsigned*)(ws + B_IMSK))[n * RR + r0] = m;
        return;
    }
    idx -= 8192;
    if (idx < RR) {  // room footprint bitmasks (48 bits) + 1/room_size
        unsigned long long m = 0ull;
        int cnt = 0;
        for (int j = 0; j < WW * HH; ++j)
            if (rt[idx * 9 * 48 + j] != 0.f) { m |= (1ull << j); ++cnt; }
        ((unsigned long long*)(ws + B_RAUX))[idx] = m;
        ((float*)(ws + B_RINV))[idx] = 1.f / (float)cnt;
    }
}

// ---------------------------------------------------------------------------
// ROUND-14 FUSED CONV: round-4's DMA-weight pipeline (measured 198us, the
// session's fastest conv — ledger audit showed rounds 6-7 abandoned it for
// the 218us reg-B variant on mistaken arithmetic) combined with round-8's
// in-kernel X gather (measured cost-neutral, deletes build_x).
//  * Weights stream through s_B[2] via global_load_lds: 25 x 8KB phases,
//    each phase = 2 ksteps; per-phase __syncthreads (implicit vmcnt drain)
//    is the double-buffer handshake. One DMA stream per block (no per-wave
//    redundant B loads).
//  * X built by threads 0-223 from the ~4-room intersect mask.
//  * LDS 45.8KB -> 3 blocks/CU; (256,3); VGPR ~68 (round-4 measured).
// ---------------------------------------------------------------------------
__global__ __launch_bounds__(256, 3) void fused_conv(
    const unsigned* __restrict__ imask, const float* __restrict__ rt,
    const float* __restrict__ emb, const short* __restrict__ wAll,
    const float* __restrict__ bc1, const float* __restrict__ bc2,
    const float* __restrict__ bc3, const int* __restrict__ pos,
    const unsigned long long* __restrict__ rmask, float* __restrict__ feat)
{
    __shared__ __align__(16) short s_Y1[120 * 72];   // 17280 B, paired-channel
    __shared__ __align__(16) short s_u[80 * 72];     // X[224][24] then Y2[80][72]
    __shared__ __align__(16) short s_B[2][4096];     // weight phase double-buffer
    __shared__ float s_feat[64];

    const int tid = threadIdx.x;
    const int lane = tid & 63;
    const int wv = tid >> 6;
    const int ml = lane & 15;
    const int q = lane >> 4;
    const int room = blockIdx.x;
    const int n = blockIdx.y;

    const int px = pos[(n * RR + room) * 2 + 0];
    const int py = pos[(n * RR + room) * 2 + 1];

    const char* wB = (const char*)wAll;
    // DMA one 8KB weight phase into its parity buffer (2KB per wave, 2x1KB)
    auto dma = [&](int ph) {
        const char* src = wB + (size_t)ph * 8192 + wv * 2048 + lane * 16;
        short* d0 = &s_B[ph & 1][wv * 1024];
        __builtin_amdgcn_global_load_lds(
            (const __attribute__((address_space(1))) unsigned int*)src,
            (__attribute__((address_space(3))) unsigned int*)d0, 16, 0, 0);
        __builtin_amdgcn_global_load_lds(
            (const __attribute__((address_space(1))) unsigned int*)(src + 1024),
            (__attribute__((address_space(3))) unsigned int*)(d0 + 512), 16, 0, 0);
    };

    dma(0);

    // ---- build X tile in-kernel: threads 0..223, one 16-channel pixel ----
    {
        const unsigned mk0 = imask[n * RR + room];  // uniform
        if (tid < 224) {
            const int row = tid / 14, col = tid - (tid / 14) * 14;
            const int gx = px - 4 + row, gy = py - 4 + col;
            float a[16];
#pragma unroll
            for (int c = 0; c < 16; ++c) a[c] = 0.f;
            a[9] = ((unsigned)gx < (unsigned)MXY && (unsigned)gy < (unsigned)MXY) ? 1.f : 0.f;

            unsigned mm = mk0;
            while (mm) {
                const int r = __builtin_ctz(mm);
                mm &= mm - 1;
                const int rpx = pos[(n * RR + r) * 2 + 0];  // uniform -> s_load
                const int rpy = pos[(n * RR + r) * 2 + 1];
                const int w = gx - rpx, h = gy - rpy;
                if ((unsigned)w < (unsigned)WW && (unsigned)h < (unsigned)HH) {
                    const int j = w * HH + h;
                    const float* rr = rt + r * 9 * 48;
#pragma unroll
                    for (int c = 0; c < 9; ++c) a[c] += rr[c * 48 + j];
                    const float mv = rr[j];  // channel 0 = room_map
#pragma unroll
                    for (int e = 0; e < EMB; ++e) a[10 + e] += emb[r * EMB + e] * mv;
                }
            }
            short o[16];
#pragma unroll
            for (int c = 0; c < 16; ++c) o[c] = f2b(a[c]);
            *reinterpret_cast<uint4*>(&s_u[tid * 24 + 0]) = *reinterpret_cast<uint4*>(o);
            *reinterpret_cast<uint4*>(&s_u[tid * 24 + 8]) = *reinterpret_cast<uint4*>(o + 8);
        }
    }
    __syncthreads();  // X staged, weight phase 0 resident

    // ================= conv1: 5x5, X(16ch) -> Y1 12x10x64 =================
    {
        int prow[2], pcol[2];
#pragma unroll
        for (int i = 0; i < 2; ++i) {
            int p = wv * 32 + i * 16 + ml;
            if (p > 119) p = 119;  // pad px: duplicate compute, discarded
            prow[i] = p / 10; pcol[i] = p - prow[i] * 10;
        }
        floatx4 acc1[2][4] = {};

#pragma unroll
        for (int t = 0; t < 7; ++t) {
            dma(t + 1);  // phases 1..7 (7 = conv2 ksteps 0-1)
            const short* sb = s_B[t & 1];
#pragma unroll
            for (int kb = 0; kb < 2; ++kb) {
                const int kk = t * 2 + kb;
                bf16x8 Bf[4];
#pragma unroll
                for (int j2 = 0; j2 < 4; ++j2)
                    Bf[j2] = *reinterpret_cast<const bf16x8*>(&sb[kb * 2048 + (j2 * 64 + lane) * 8]);
                int tap = kk * 2 + (q >> 1);
                if (tap > 24) tap = 24;  // padded-tail weights are zero
                const int chb = (q & 1) * 8;
                const int dx = tap / 5, dy = tap - (tap / 5) * 5;
                __builtin_amdgcn_s_setprio(1);
#pragma unroll
                for (int i = 0; i < 2; ++i) {
                    bf16x8 A = *reinterpret_cast<const bf16x8*>(
                        &s_u[((prow[i] + dx) * 14 + (pcol[i] + dy)) * 24 + chb]);
#pragma unroll
                    for (int j2 = 0; j2 < 4; ++j2)
                        acc1[i][j2] = __builtin_amdgcn_mfma_f32_16x16x32_bf16(
                            A, Bf[j2], acc1[i][j2], 0, 0, 0);
                }
                __builtin_amdgcn_s_setprio(0);
            }
            if (t == 6) {  // epilogue: bias+relu, b64 paired-channel stores
                float b4[4];
#pragma unroll
                for (int j2 = 0; j2 < 4; ++j2) b4[j2] = bc1[j2 * 16 + ml];
#pragma unroll
                for (int i = 0; i < 2; ++i)
#pragma unroll
                    for (int r = 0; r < 4; ++r) {
                        int p = wv * 32 + i * 16 + q * 4 + r;
                        if (p < 120) {
                            unsigned lo = (unsigned)(unsigned short)f2b(fmaxf(acc1[i][0][r] + b4[0], 0.f))
                                        | ((unsigned)(unsigned short)f2b(fmaxf(acc1[i][1][r] + b4[1], 0.f)) << 16);
                            unsigned hi = (unsigned)(unsigned short)f2b(fmaxf(acc1[i][2][r] + b4[2], 0.f))
                                        | ((unsigned)(unsigned short)f2b(fmaxf(acc1[i][3][r] + b4[3], 0.f)) << 16);
                            *reinterpret_cast<uint2*>(&s_Y1[p * 72 + ml * 4]) = make_uint2(lo, hi);
                        }
                    }
            }
            __syncthreads();
        }
    }

    // ===== conv2: 3x3, Y1 -> Y2 10x8x64 (tiles 0-3 owned, tile 4 n-split) ==
    {
        int prowA, pcolA, prowB, pcolB;
        {
            int p0 = wv * 16 + ml; prowA = p0 >> 3; pcolA = p0 & 7;
            int p1 = 64 + ml;      prowB = p1 >> 3; pcolB = p1 & 7;
        }
        floatx4 acc2[4] = {};
        floatx4 acc2s = {};

#pragma unroll
        for (int t = 0; t < 9; ++t) {
            dma(8 + t);  // phases 8..16 (16 = conv3 ksteps 0-1)
            const short* sb = s_B[(7 + t) & 1];
#pragma unroll
            for (int kb = 0; kb < 2; ++kb) {
                bf16x8 Bf[4];
#pragma unroll
                for (int j2 = 0; j2 < 4; ++j2)
                    Bf[j2] = *reinterpret_cast<const bf16x8*>(&sb[kb * 2048 + (j2 * 64 + lane) * 8]);
                // 5th-tile B frag: wave-uniform LDS base (rule #20 safe)
                bf16x8 B4 = *reinterpret_cast<const bf16x8*>(&sb[kb * 2048 + (wv * 64 + lane) * 8]);
                const int kk = t * 2 + kb;
                const int tap = kk >> 1;
                const int chb = (kk & 1) * 32 + q * 8;
                const int dx = tap / 3, dy = tap - (tap / 3) * 3;
                bf16x8 A0 = *reinterpret_cast<const bf16x8*>(
                    &s_Y1[((prowA + dx) * 10 + (pcolA + dy)) * 72 + chb]);
                bf16x8 A4 = *reinterpret_cast<const bf16x8*>(
                    &s_Y1[((prowB + dx) * 10 + (pcolB + dy)) * 72 + chb]);
                __builtin_amdgcn_s_setprio(1);
#pragma unroll
                for (int j2 = 0; j2 < 4; ++j2)
                    acc2[j2] = __builtin_amdgcn_mfma_f32_16x16x32_bf16(A0, Bf[j2], acc2[j2], 0, 0, 0);
                acc2s = __builtin_amdgcn_mfma_f32_16x16x32_bf16(A4, B4, acc2s, 0, 0, 0);
                __builtin_amdgcn_s_setprio(0);
            }
            if (t == 8) {  // epilogue into s_u (X is dead)
                float b4[4];
#pragma unroll
                for (int j2 = 0; j2 < 4; ++j2) b4[j2] = bc2[j2 * 16 + ml];
#pragma unroll
                for (int r = 0; r < 4; ++r) {
                    int p = wv * 16 + q * 4 + r;
                    unsigned lo = (unsigned)(unsigned short)f2b(fmaxf(acc2[0][r] + b4[0], 0.f))
                                | ((unsigned)(unsigned short)f2b(fmaxf(acc2[1][r] + b4[1], 0.f)) << 16);
                    unsigned hi = (unsigned)(unsigned short)f2b(fmaxf(acc2[2][r] + b4[2], 0.f))
                                | ((unsigned)(unsigned short)f2b(fmaxf(acc2[3][r] + b4[3], 0.f)) << 16);
                    *reinterpret_cast<uint2*>(&s_u[p * 72 + ml * 4]) = make_uint2(lo, hi);
                }
                float bt = bc2[wv * 16 + ml];
#pragma unroll
                for (int r = 0; r < 4; ++r) {
                    int p = 64 + q * 4 + r;
                    s_u[p * 72 + ml * 4 + wv] = f2b(fmaxf(acc2s[r] + bt, 0.f));
                }
                if (tid < 64) s_feat[tid] = 0.f;
            }
            __syncthreads();
        }
    }

    // ====== conv3: 3x3, Y2 -> 8x6 masked room-sum (waves 0-2) ======
    {
        int prow3, pcol3;
        {
            int p0 = wv * 16 + ml;
            prow3 = p0 / 6; pcol3 = p0 - (p0 / 6) * 6;
        }
        floatx4 acc3[4] = {};

#pragma unroll
        for (int t = 0; t < 9; ++t) {
            if (t < 8) dma(17 + t);  // phases 17..24
            const short* sb = s_B[(16 + t) & 1];
            if (wv < 3) {
#pragma unroll
                for (int kb = 0; kb < 2; ++kb) {
                    const int kk = t * 2 + kb;
                    bf16x8 Bf[4];
#pragma unroll
                    for (int j2 = 0; j2 < 4; ++j2)
                        Bf[j2] = *reinterpret_cast<const bf16x8*>(&sb[kb * 2048 + (j2 * 64 + lane) * 8]);
                    const int tap = kk >> 1;
                    const int chb = (kk & 1) * 32 + q * 8;
                    const int dx = tap / 3, dy = tap - (tap / 3) * 3;
                    bf16x8 A = *reinterpret_cast<const bf16x8*>(
                        &s_u[((prow3 + dx) * 8 + (pcol3 + dy)) * 72 + chb]);
                    __builtin_amdgcn_s_setprio(1);
#pragma unroll
                    for (int j2 = 0; j2 < 4; ++j2)
                        acc3[j2] = __builtin_amdgcn_mfma_f32_16x16x32_bf16(A, Bf[j2], acc3[j2], 0, 0, 0);
                    __builtin_amdgcn_s_setprio(0);
                }
            }
            if (t == 8 && wv < 3) {  // masked reduce
                float b4[4];
#pragma unroll
                for (int j2 = 0; j2 < 4; ++j2) b4[j2] = bc3[j2 * 16 + ml];
                float part[4] = {0.f, 0.f, 0.f, 0.f};
                const unsigned long long mk = rmask[room];
#pragma unroll
                for (int r = 0; r < 4; ++r) {
                    int p = wv * 16 + q * 4 + r;  // == w*6+h == mask bit index
                    if ((mk >> p) & 1ull) {
#pragma unroll
                        for (int j2 = 0; j2 < 4; ++j2)
                            part[j2] += fmaxf(acc3[j2][r] + b4[j2], 0.f);
                    }
                }
#pragma unroll
                for (int j2 = 0; j2 < 4; ++j2) {
                    part[j2] += __shfl_xor(part[j2], 16);
                    part[j2] += __shfl_xor(part[j2], 32);
                }
                if (q == 0) {
#pragma unroll
                    for (int j2 = 0; j2 < 4; ++j2)
                        atomicAdd(&s_feat[j2 * 16 + ml], part[j2]);  // 3 contenders
                }
            }
            __syncthreads();
        }
    }

    if (tid < 64)
        feat[((size_t)n * RR + room) * 64 + tid] = s_feat[tid];
}

// ---------------------------------------------------------------------------
// Head split (round-13, proven): head_rooms = 4 blocks/sample, 8 rooms each
// (amortizes the 96KB head-weight read; 1-room fusion was L2-bound, r12).
// Partial room-sums to PRIVATE slots (no atomics/zeroing); head_fc sums 4.
// ---------------------------------------------------------------------------
__global__ __launch_bounds__(256) void head_rooms(const float* __restrict__ feat,
                                                  const float* __restrict__ HEAD,
                                                  const float* __restrict__ rinv,
                                                  const float* __restrict__ b1,
                                                  const float* __restrict__ b2,
                                                  float* __restrict__ ssum)
{
    __shared__ __align__(16) float s_feat[8 * 64];
    __shared__ __align__(16) float s_h1[8 * 128];
    __shared__ __align__(16) float s_s[2 * 128];

    const int qr = blockIdx.x;   // 0..3 -> rooms qr*8 .. qr*8+7
    const int n = blockIdx.y;
    const int tid = threadIdx.x;
    const float* W1t = HEAD + F_WR1T;
    const float* W2t = HEAD + F_WR2T;

    for (int i = tid; i < 8 * 64; i += 256)
        s_feat[i] = feat[(size_t)n * RR * 64 + qr * 512 + i] * rinv[qr * 8 + (i >> 6)];
    __syncthreads();

    const int o = tid & 127;
    const int rh = tid >> 7;     // rooms rh*4 .. rh*4+3 (local)

    float acc[4];
#pragma unroll
    for (int r = 0; r < 4; ++r) acc[r] = b1[o];
    for (int c4 = 0; c4 < 16; ++c4) {
        float w0 = W1t[(c4 * 4 + 0) * 128 + o];
        float w1 = W1t[(c4 * 4 + 1) * 128 + o];
        float w2 = W1t[(c4 * 4 + 2) * 128 + o];
        float w3 = W1t[(c4 * 4 + 3) * 128 + o];
#pragma unroll
        for (int r = 0; r < 4; ++r) {
            float4 f = *reinterpret_cast<const float4*>(&s_feat[(rh * 4 + r) * 64 + c4 * 4]);
            acc[r] += f.x * w0 + f.y * w1 + f.z * w2 + f.w * w3;
        }
    }
#pragma unroll
    for (int r = 0; r < 4; ++r) s_h1[(rh * 4 + r) * 128 + o] = fmaxf(acc[r], 0.f);
    __syncthreads();

#pragma unroll
    for (int r = 0; r < 4; ++r) acc[r] = b2[o];
    for (int c4 = 0; c4 < 32; ++c4) {
        float w0 = W2t[(c4 * 4 + 0) * 128 + o];
        float w1 = W2t[(c4 * 4 + 1) * 128 + o];
        float w2 = W2t[(c4 * 4 + 2) * 128 + o];
        float w3 = W2t[(c4 * 4 + 3) * 128 + o];
#pragma unroll
        for (int r = 0; r < 4; ++r) {
            float4 f = *reinterpret_cast<const float4*>(&s_h1[(rh * 4 + r) * 128 + c4 * 4]);
            acc[r] += f.x * w0 + f.y * w1 + f.z * w2 + f.w * w3;
        }
    }
    float ps = 0.f;
#pragma unroll
    for (int r = 0; r < 4; ++r) ps += fmaxf(acc[r], 0.f);
    s_s[rh * 128 + o] = ps;
    __syncthreads();
    if (tid < 128)
        ssum[((size_t)n * 4 + qr) * 128 + tid] = s_s[tid] + s_s[128 + tid];
}

__global__ __launch_bounds__(256) void head_fc(const float* __restrict__ ssum,
                                               const float* __restrict__ HEAD,
                                               const float* __restrict__ bf1,
                                               const float* __restrict__ bf2,
                                               float* __restrict__ outp)
{
    __shared__ __align__(16) float s_sf[128];
    __shared__ __align__(16) float s_t1[256];

    const int n = blockIdx.x;
    const int tid = threadIdx.x;
    const float* F1t = HEAD + F_F1T;
    const float* F2t = HEAD + F_F2T;

    if (tid < 128) {
        const float* s0 = ssum + (size_t)n * 4 * 128 + tid;
        s_sf[tid] = (s0[0] + s0[128]) + (s0[256] + s0[384]);
    }
    __syncthreads();

    {
        float a = bf1[tid];
#pragma unroll 4
        for (int c4 = 0; c4 < 32; ++c4) {
            float4 f = *reinterpret_cast<const float4*>(&s_sf[c4 * 4]);
            a += f.x * F1t[(c4 * 4 + 0) * 256 + tid];
            a += f.y * F1t[(c4 * 4 + 1) * 256 + tid];
            a += f.z * F1t[(c4 * 4 + 2) * 256 + tid];
            a += f.w * F1t[(c4 * 4 + 3) * 256 + tid];
        }
        s_t1[tid] = fmaxf(a, 0.f);
    }
    __syncthreads();

    {
        float a = bf2[tid];
#pragma unroll 4
        for (int c4 = 0; c4 < 64; ++c4) {
            float4 f = *reinterpret_cast<const float4*>(&s_t1[c4 * 4]);
            a += f.x * F2t[(c4 * 4 + 0) * 256 + tid];
            a += f.y * F2t[(c4 * 4 + 1) * 256 + tid];
            a += f.z * F2t[(c4 * 4 + 2) * 256 + tid];
            a += f.w * F2t[(c4 * 4 + 3) * 256 + tid];
        }
        outp[(size_t)n * 256 + tid] = a;
    }
}

// ---------------------------------------------------------------------------
extern "C" void kernel_launch(void* const* d_in, const int* in_sizes, int n_in,
                              void* d_out, int out_size, void* d_ws, size_t ws_size,
                              hipStream_t stream)
{
    const int* pos = (const int*)d_in[0];
    const float* rt = (const float*)d_in[1];
    const float* emb = (const float*)d_in[2];
    const float* w1 = (const float*)d_in[3];
    const float* bc1 = (const float*)d_in[4];
    const float* w2 = (const float*)d_in[5];
    const float* bc2 = (const float*)d_in[6];
    const float* w3 = (const float*)d_in[7];
    const float* bc3 = (const float*)d_in[8];
    const float* wr1 = (const float*)d_in[9];
    const float* br1 = (const float*)d_in[10];
    const float* wr2 = (const float*)d_in[11];
    const float* br2 = (const float*)d_in[12];
    const float* wf1 = (const float*)d_in[13];
    const float* bf1 = (const float*)d_in[14];
    const float* wf2 = (const float*)d_in[15];
    const float* bf2 = (const float*)d_in[16];
    float* out = (float*)d_out;
    char* ws = (char*)d_ws;

    // merged prep: 225280 weight + 8192 imask + 32 room ids
    prep_all<<<913, 256, 0, stream>>>(w1, w2, w3, wr1, wr2, wf1, wf2, rt, pos, ws);

    const short* WALL = (const short*)(ws + B_W1F);
    const unsigned long long* RMASK = (const unsigned long long*)(ws + B_RAUX);
    const float* RINV = (const float*)(ws + B_RINV);
    const float* HEAD = (const float*)(ws + B_HEAD);
    float* FEAT = (float*)(ws + B_FEAT);
    unsigned* IMSK = (unsigned*)(ws + B_IMSK);
    float* SSUM = (float*)(ws + B_SSUM);

    fused_conv<<<dim3(RR, NB), 256, 0, stream>>>(IMSK, rt, emb, WALL,
                                                 bc1, bc2, bc3, pos, RMASK, FEAT);

    head_rooms<<<dim3(4, NB), 256, 0, stream>>>(FEAT, HEAD, RINV, br1, br2, SSUM);
    head_fc<<<NB, 256, 0, stream>>>(SSUM, HEAD, bf1, bf2, out);
}

// Round 15
// 272.228 us; speedup vs baseline: 3.2364x; 1.0181x over previous
//
#include <hip/hip_runtime.h>
#include <hip/hip_bf16.h>
#include <cstddef>

// Problem constants
#define NB 256   // batch
#define RR 32    // rooms
#define WW 8     // room width
#define HH 6     // room height
#define MXY 72   // map extent
#define EMB 6
#define CIN1 16  // 9 + 1 + 6

typedef __bf16 bf16x8 __attribute__((ext_vector_type(8)));
typedef float floatx4 __attribute__((ext_vector_type(4)));

// --- Workspace layout (byte offsets) ---------------------------------------
// Conv weights packed as 50 contiguous 4KB ksteps:
//   conv1: ksteps 0..13 (13 real + 1 zero-pad) ; conv2: 14..31 ; conv3: 32..49
static const size_t B_W1F  = 0;
static const size_t B_W2F  = 57344;
static const size_t B_W3F  = 131072;
static const size_t B_RAUX = 204800;    // room masks (32 u64)
static const size_t B_RINV = 205056;    // 1/room_size (32 f32)
static const size_t B_HEAD = 205312;    // fp32 head weights, 122880 floats
static const size_t F_WR1T = 0;         // (64,128)
static const size_t F_WR2T = 8192;      // (128,128)
static const size_t F_F1T  = 24576;     // (128,256)
static const size_t F_F2T  = 57344;     // (256,256)
static const size_t B_FEAT = 696832;    // (256,32,64) f32 = 2 MB
static const size_t B_IMSK = 2793984;   // (256,32) u32 intersect masks (32 KB)
static const size_t B_SSUM = 2826752;   // (256,4,128) f32 partial slots (512 KB)

__device__ inline short f2b(float f) {
    unsigned u = __builtin_bit_cast(unsigned, f);
    unsigned r = (u + 0x7fffu + ((u >> 16) & 1u)) >> 16;
    return (short)r;
}

// ---------------------------------------------------------------------------
// ONE merged prep kernel. Disjoint index ranges:
//   [0, 225280)          weights -> bf16 B-frag order + head transposes
//   [225280, 233472)     per-(sample,room) 32-bit intersect masks
//   [233472, 233504)     room footprint bitmasks + 1/room_size
// Fragment order: [kk][ntile][lane][j] ; virtual k = kk*32 + (lane>>4)*8 + j
// oc = ntile*16 + (lane&15).
// conv1: (tap,ci) natural. conv2/3: position cp -> channel (cp>>2)+(cp&3)*16
// (paired-channel layout Y1/Y2 are written in).
// ---------------------------------------------------------------------------
__global__ void prep_all(const float* __restrict__ w1, const float* __restrict__ w2,
                         const float* __restrict__ w3, const float* __restrict__ wr1,
                         const float* __restrict__ wr2, const float* __restrict__ wf1,
                         const float* __restrict__ wf2, const float* __restrict__ rt,
                         const int* __restrict__ pos, char* __restrict__ ws)
{
    short* W1F = (short*)(ws + B_W1F);
    short* W2F = (short*)(ws + B_W2F);
    short* W3F = (short*)(ws + B_W3F);
    float* HEAD = (float*)(ws + B_HEAD);

    int idx = blockIdx.x * 256 + threadIdx.x;
    if (idx < 28672) {  // conv1: 14 ksteps (padded), CIN=16, taps 0..24 real
        int j = idx & 7, lane = (idx >> 3) & 63, nt = (idx >> 9) & 3, kk = idx >> 11;
        int k = kk * 32 + (lane >> 4) * 8 + j;
        int oc = nt * 16 + (lane & 15);
        int tap = k >> 4, ci = k & 15;
        float v = (tap < 25) ? w1[(oc * 16 + ci) * 25 + tap] : 0.f;
        W1F[idx] = f2b(v);
        return;
    }
    idx -= 28672;
    if (idx < 36864) {  // conv2: 18 ksteps, CIN=64, 9 taps, permuted ci
        int j = idx & 7, lane = (idx >> 3) & 63, nt = (idx >> 9) & 3, kk = idx >> 11;
        int k = kk * 32 + (lane >> 4) * 8 + j;
        int oc = nt * 16 + (lane & 15);
        int tap = k >> 6, cp = k & 63;
        int ci = (cp >> 2) + (cp & 3) * 16;
        W2F[idx] = f2b(w2[(oc * 64 + ci) * 9 + tap]);
        return;
    }
    idx -= 36864;
    if (idx < 36864) {  // conv3, permuted ci
        int j = idx & 7, lane = (idx >> 3) & 63, nt = (idx >> 9) & 3, kk = idx >> 11;
        int k = kk * 32 + (lane >> 4) * 8 + j;
        int oc = nt * 16 + (lane & 15);
        int tap = k >> 6, cp = k & 63;
        int ci = (cp >> 2) + (cp & 3) * 16;
        W3F[idx] = f2b(w3[(oc * 64 + ci) * 9 + tap]);
        return;
    }
    idx -= 36864;
    if (idx < 8192)  { int o = idx & 127, c = idx >> 7; HEAD[F_WR1T + idx] = wr1[o * 64 + c]; return; }
    idx -= 8192;
    if (idx < 16384) { int o = idx & 127, c = idx >> 7; HEAD[F_WR2T + idx] = wr2[o * 128 + c]; return; }
    idx -= 16384;
    if (idx < 32768) { int o = idx & 255, c = idx >> 8; HEAD[F_F1T + idx] = wf1[o * 128 + c]; return; }
    idx -= 32768;
    if (idx < 65536) { int o = idx & 255, c = idx >> 8; HEAD[F_F2T + idx] = wf2[o * 256 + c]; return; }
    idx -= 65536;
    if (idx < 8192) {  // intersect masks: rooms touching the 16x14 X halo tile
        const int n = idx >> 5, r0 = idx & 31;
        const int px0 = pos[(n * RR + r0) * 2 + 0];
        const int py0 = pos[(n * RR + r0) * 2 + 1];
        unsigned m = 0;
        for (int r = 0; r < RR; ++r) {
            int rpx = pos[(n * RR + r) * 2 + 0];
            int rpy = pos[(n * RR + r) * 2 + 1];
            if (rpx >= px0 - 11 && rpx <= px0 + 11 && rpy >= py0 - 9 && rpy <= py0 + 9)
                m |= 1u << r;
        }
        ((unsigned*)(ws + B_IMSK))[n * RR + r0] = m;
        return;
    }
    idx -= 8192;
    if (idx < RR) {  // room footprint bitmasks (48 bits) + 1/room_size
        unsigned long long m = 0ull;
        int cnt = 0;
        for (int j = 0; j < WW * HH; ++j)
            if (rt[idx * 9 * 48 + j] != 0.f) { m |= (1ull << j); ++cnt; }
        ((unsigned long long*)(ws + B_RAUX))[idx] = m;
        ((float*)(ws + B_RINV))[idx] = 1.f / (float)cnt;
    }
}

// ---------------------------------------------------------------------------
// ROUND-15 FUSED CONV: round-14's DMA pipeline (197us) at 1-KSTEP phase
// granularity — the pre-registered round-4 fallback, never yet tested.
//  * s_B[2][2048]: each phase DMAs ONE 4KB kstep; LDS 45.4 -> 37.2 KB ->
//    4 blocks/CU (was 3). 33% more TLP to cover each barrier's DMA-drain.
//  * Cost: 50 barriers (was 26), per-phase compute halves. Bet: the 4th
//    resident block covers the shorter-but-more-frequent stalls.
//  * Tripwire: conv >= 205us => barrier frequency beats TLP, revert to r14.
// X built in-kernel (r8); head split (r13) unchanged.
// ---------------------------------------------------------------------------
__global__ __launch_bounds__(256, 4) void fused_conv(
    const unsigned* __restrict__ imask, const float* __restrict__ rt,
    const float* __restrict__ emb, const short* __restrict__ wAll,
    const float* __restrict__ bc1, const float* __restrict__ bc2,
    const float* __restrict__ bc3, const int* __restrict__ pos,
    const unsigned long long* __restrict__ rmask, float* __restrict__ feat)
{
    __shared__ __align__(16) short s_Y1[120 * 72];   // 17280 B, paired-channel
    __shared__ __align__(16) short s_u[80 * 72];     // X[224][24] then Y2[80][72]
    __shared__ __align__(16) short s_B[2][2048];     // 1-kstep weight dbuf (8KB)
    __shared__ float s_feat[64];

    const int tid = threadIdx.x;
    const int lane = tid & 63;
    const int wv = tid >> 6;
    const int ml = lane & 15;
    const int q = lane >> 4;
    const int room = blockIdx.x;
    const int n = blockIdx.y;

    const int px = pos[(n * RR + room) * 2 + 0];
    const int py = pos[(n * RR + room) * 2 + 1];

    const char* wB = (const char*)wAll;
    // DMA one 4KB kstep into its parity buffer (1KB per wave)
    auto dma = [&](int k) {
        const char* src = wB + (size_t)k * 4096 + wv * 1024 + lane * 16;
        __builtin_amdgcn_global_load_lds(
            (const __attribute__((address_space(1))) unsigned int*)src,
            (__attribute__((address_space(3))) unsigned int*)&s_B[k & 1][wv * 512],
            16, 0, 0);
    };

    dma(0);

    // ---- build X tile in-kernel: threads 0..223, one 16-channel pixel ----
    {
        const unsigned mk0 = imask[n * RR + room];  // uniform
        if (tid < 224) {
            const int row = tid / 14, col = tid - (tid / 14) * 14;
            const int gx = px - 4 + row, gy = py - 4 + col;
            float a[16];
#pragma unroll
            for (int c = 0; c < 16; ++c) a[c] = 0.f;
            a[9] = ((unsigned)gx < (unsigned)MXY && (unsigned)gy < (unsigned)MXY) ? 1.f : 0.f;

            unsigned mm = mk0;
            while (mm) {
                const int r = __builtin_ctz(mm);
                mm &= mm - 1;
                const int rpx = pos[(n * RR + r) * 2 + 0];  // uniform -> s_load
                const int rpy = pos[(n * RR + r) * 2 + 1];
                const int w = gx - rpx, h = gy - rpy;
                if ((unsigned)w < (unsigned)WW && (unsigned)h < (unsigned)HH) {
                    const int j = w * HH + h;
                    const float* rr = rt + r * 9 * 48;
#pragma unroll
                    for (int c = 0; c < 9; ++c) a[c] += rr[c * 48 + j];
                    const float mv = rr[j];  // channel 0 = room_map
#pragma unroll
                    for (int e = 0; e < EMB; ++e) a[10 + e] += emb[r * EMB + e] * mv;
                }
            }
            short o[16];
#pragma unroll
            for (int c = 0; c < 16; ++c) o[c] = f2b(a[c]);
            *reinterpret_cast<uint4*>(&s_u[tid * 24 + 0]) = *reinterpret_cast<uint4*>(o);
            *reinterpret_cast<uint4*>(&s_u[tid * 24 + 8]) = *reinterpret_cast<uint4*>(o + 8);
        }
    }
    __syncthreads();  // X staged, weight kstep 0 resident

    // ================= conv1: 5x5, X(16ch) -> Y1 12x10x64 =================
    {
        int prow[2], pcol[2];
#pragma unroll
        for (int i = 0; i < 2; ++i) {
            int p = wv * 32 + i * 16 + ml;
            if (p > 119) p = 119;  // pad px: duplicate compute, discarded
            prow[i] = p / 10; pcol[i] = p - prow[i] * 10;
        }
        floatx4 acc1[2][4] = {};

#pragma unroll
        for (int k = 0; k < 14; ++k) {  // global ksteps 0..13 (13 = zero pad)
            dma(k + 1);
            const short* sb = s_B[k & 1];
            bf16x8 Bf[4];
#pragma unroll
            for (int j2 = 0; j2 < 4; ++j2)
                Bf[j2] = *reinterpret_cast<const bf16x8*>(&sb[(j2 * 64 + lane) * 8]);
            int tap = k * 2 + (q >> 1);
            if (tap > 24) tap = 24;  // padded-tail weights are zero
            const int chb = (q & 1) * 8;
            const int dx = tap / 5, dy = tap - (tap / 5) * 5;
            __builtin_amdgcn_s_setprio(1);
#pragma unroll
            for (int i = 0; i < 2; ++i) {
                bf16x8 A = *reinterpret_cast<const bf16x8*>(
                    &s_u[((prow[i] + dx) * 14 + (pcol[i] + dy)) * 24 + chb]);
#pragma unroll
                for (int j2 = 0; j2 < 4; ++j2)
                    acc1[i][j2] = __builtin_amdgcn_mfma_f32_16x16x32_bf16(
                        A, Bf[j2], acc1[i][j2], 0, 0, 0);
            }
            __builtin_amdgcn_s_setprio(0);
            if (k == 13) {  // epilogue: bias+relu, b64 paired-channel stores
                float b4[4];
#pragma unroll
                for (int j2 = 0; j2 < 4; ++j2) b4[j2] = bc1[j2 * 16 + ml];
#pragma unroll
                for (int i = 0; i < 2; ++i)
#pragma unroll
                    for (int r = 0; r < 4; ++r) {
                        int p = wv * 32 + i * 16 + q * 4 + r;
                        if (p < 120) {
                            unsigned lo = (unsigned)(unsigned short)f2b(fmaxf(acc1[i][0][r] + b4[0], 0.f))
                                        | ((unsigned)(unsigned short)f2b(fmaxf(acc1[i][1][r] + b4[1], 0.f)) << 16);
                            unsigned hi = (unsigned)(unsigned short)f2b(fmaxf(acc1[i][2][r] + b4[2], 0.f))
                                        | ((unsigned)(unsigned short)f2b(fmaxf(acc1[i][3][r] + b4[3], 0.f)) << 16);
                            *reinterpret_cast<uint2*>(&s_Y1[p * 72 + ml * 4]) = make_uint2(lo, hi);
                        }
                    }
            }
            __syncthreads();
        }
    }

    // ===== conv2: 3x3, Y1 -> Y2 10x8x64 (tiles 0-3 owned, tile 4 n-split) ==
    {
        int prowA, pcolA, prowB, pcolB;
        {
            int p0 = wv * 16 + ml; prowA = p0 >> 3; pcolA = p0 & 7;
            int p1 = 64 + ml;      prowB = p1 >> 3; pcolB = p1 & 7;
        }
        floatx4 acc2[4] = {};
        floatx4 acc2s = {};

#pragma unroll
        for (int k = 14; k < 32; ++k) {  // global ksteps 14..31
            dma(k + 1);
            const short* sb = s_B[k & 1];
            const int kk = k - 14;
            bf16x8 Bf[4];
#pragma unroll
            for (int j2 = 0; j2 < 4; ++j2)
                Bf[j2] = *reinterpret_cast<const bf16x8*>(&sb[(j2 * 64 + lane) * 8]);
            // 5th-tile B frag: wave-uniform LDS base (rule #20 safe)
            bf16x8 B4 = *reinterpret_cast<const bf16x8*>(&sb[(wv * 64 + lane) * 8]);
            const int tap = kk >> 1;
            const int chb = (kk & 1) * 32 + q * 8;
            const int dx = tap / 3, dy = tap - (tap / 3) * 3;
            bf16x8 A0 = *reinterpret_cast<const bf16x8*>(
                &s_Y1[((prowA + dx) * 10 + (pcolA + dy)) * 72 + chb]);
            bf16x8 A4 = *reinterpret_cast<const bf16x8*>(
                &s_Y1[((prowB + dx) * 10 + (pcolB + dy)) * 72 + chb]);
            __builtin_amdgcn_s_setprio(1);
#pragma unroll
            for (int j2 = 0; j2 < 4; ++j2)
                acc2[j2] = __builtin_amdgcn_mfma_f32_16x16x32_bf16(A0, Bf[j2], acc2[j2], 0, 0, 0);
            acc2s = __builtin_amdgcn_mfma_f32_16x16x32_bf16(A4, B4, acc2s, 0, 0, 0);
            __builtin_amdgcn_s_setprio(0);
            if (k == 31) {  // epilogue into s_u (X is dead)
                float b4[4];
#pragma unroll
                for (int j2 = 0; j2 < 4; ++j2) b4[j2] = bc2[j2 * 16 + ml];
#pragma unroll
                for (int r = 0; r < 4; ++r) {
                    int p = wv * 16 + q * 4 + r;
                    unsigned lo = (unsigned)(unsigned short)f2b(fmaxf(acc2[0][r] + b4[0], 0.f))
                                | ((unsigned)(unsigned short)f2b(fmaxf(acc2[1][r] + b4[1], 0.f)) << 16);
                    unsigned hi = (unsigned)(unsigned short)f2b(fmaxf(acc2[2][r] + b4[2], 0.f))
                                | ((unsigned)(unsigned short)f2b(fmaxf(acc2[3][r] + b4[3], 0.f)) << 16);
                    *reinterpret_cast<uint2*>(&s_u[p * 72 + ml * 4]) = make_uint2(lo, hi);
                }
                float bt = bc2[wv * 16 + ml];
#pragma unroll
                for (int r = 0; r < 4; ++r) {
                    int p = 64 + q * 4 + r;
                    s_u[p * 72 + ml * 4 + wv] = f2b(fmaxf(acc2s[r] + bt, 0.f));
                }
                if (tid < 64) s_feat[tid] = 0.f;
            }
            __syncthreads();
        }
    }

    // ====== conv3: 3x3, Y2 -> 8x6 masked room-sum (waves 0-2) ======
    {
        int prow3, pcol3;
        {
            int p0 = wv * 16 + ml;
            prow3 = p0 / 6; pcol3 = p0 - (p0 / 6) * 6;
        }
        floatx4 acc3[4] = {};

#pragma unroll
        for (int k = 32; k < 50; ++k) {  // global ksteps 32..49
            if (k + 1 < 50) dma(k + 1);
            const short* sb = s_B[k & 1];
            const int kk = k - 32;
            if (wv < 3) {
                bf16x8 Bf[4];
#pragma unroll
                for (int j2 = 0; j2 < 4; ++j2)
                    Bf[j2] = *reinterpret_cast<const bf16x8*>(&sb[(j2 * 64 + lane) * 8]);
                const int tap = kk >> 1;
                const int chb = (kk & 1) * 32 + q * 8;
                const int dx = tap / 3, dy = tap - (tap / 3) * 3;
                bf16x8 A = *reinterpret_cast<const bf16x8*>(
                    &s_u[((prow3 + dx) * 8 + (pcol3 + dy)) * 72 + chb]);
                __builtin_amdgcn_s_setprio(1);
#pragma unroll
                for (int j2 = 0; j2 < 4; ++j2)
                    acc3[j2] = __builtin_amdgcn_mfma_f32_16x16x32_bf16(A, Bf[j2], acc3[j2], 0, 0, 0);
                __builtin_amdgcn_s_setprio(0);
            }
            if (k == 49 && wv < 3) {  // masked reduce
                float b4[4];
#pragma unroll
                for (int j2 = 0; j2 < 4; ++j2) b4[j2] = bc3[j2 * 16 + ml];
                float part[4] = {0.f, 0.f, 0.f, 0.f};
                const unsigned long long mk = rmask[room];
#pragma unroll
                for (int r = 0; r < 4; ++r) {
                    int p = wv * 16 + q * 4 + r;  // == w*6+h == mask bit index
                    if ((mk >> p) & 1ull) {
#pragma unroll
                        for (int j2 = 0; j2 < 4; ++j2)
                            part[j2] += fmaxf(acc3[j2][r] + b4[j2], 0.f);
                    }
                }
#pragma unroll
                for (int j2 = 0; j2 < 4; ++j2) {
                    part[j2] += __shfl_xor(part[j2], 16);
                    part[j2] += __shfl_xor(part[j2], 32);
                }
                if (q == 0) {
#pragma unroll
                    for (int j2 = 0; j2 < 4; ++j2)
                        atomicAdd(&s_feat[j2 * 16 + ml], part[j2]);  // 3 contenders
                }
            }
            __syncthreads();
        }
    }

    if (tid < 64)
        feat[((size_t)n * RR + room) * 64 + tid] = s_feat[tid];
}

// ---------------------------------------------------------------------------
// Head split (round-13, proven): head_rooms = 4 blocks/sample, 8 rooms each
// (amortizes the 96KB head-weight read; 1-room fusion was L2-bound, r12).
// Partial room-sums to PRIVATE slots (no atomics/zeroing); head_fc sums 4.
// ---------------------------------------------------------------------------
__global__ __launch_bounds__(256) void head_rooms(const float* __restrict__ feat,
                                                  const float* __restrict__ HEAD,
                                                  const float* __restrict__ rinv,
                                                  const float* __restrict__ b1,
                                                  const float* __restrict__ b2,
                                                  float* __restrict__ ssum)
{
    __shared__ __align__(16) float s_feat[8 * 64];
    __shared__ __align__(16) float s_h1[8 * 128];
    __shared__ __align__(16) float s_s[2 * 128];

    const int qr = blockIdx.x;   // 0..3 -> rooms qr*8 .. qr*8+7
    const int n = blockIdx.y;
    const int tid = threadIdx.x;
    const float* W1t = HEAD + F_WR1T;
    const float* W2t = HEAD + F_WR2T;

    for (int i = tid; i < 8 * 64; i += 256)
        s_feat[i] = feat[(size_t)n * RR * 64 + qr * 512 + i] * rinv[qr * 8 + (i >> 6)];
    __syncthreads();

    const int o = tid & 127;
    const int rh = tid >> 7;     // rooms rh*4 .. rh*4+3 (local)

    float acc[4];
#pragma unroll
    for (int r = 0; r < 4; ++r) acc[r] = b1[o];
    for (int c4 = 0; c4 < 16; ++c4) {
        float w0 = W1t[(c4 * 4 + 0) * 128 + o];
        float w1 = W1t[(c4 * 4 + 1) * 128 + o];
        float w2 = W1t[(c4 * 4 + 2) * 128 + o];
        float w3 = W1t[(c4 * 4 + 3) * 128 + o];
#pragma unroll
        for (int r = 0; r < 4; ++r) {
            float4 f = *reinterpret_cast<const float4*>(&s_feat[(rh * 4 + r) * 64 + c4 * 4]);
            acc[r] += f.x * w0 + f.y * w1 + f.z * w2 + f.w * w3;
        }
    }
#pragma unroll
    for (int r = 0; r < 4; ++r) s_h1[(rh * 4 + r) * 128 + o] = fmaxf(acc[r], 0.f);
    __syncthreads();

#pragma unroll
    for (int r = 0; r < 4; ++r) acc[r] = b2[o];
    for (int c4 = 0; c4 < 32; ++c4) {
        float w0 = W2t[(c4 * 4 + 0) * 128 + o];
        float w1 = W2t[(c4 * 4 + 1) * 128 + o];
        float w2 = W2t[(c4 * 4 + 2) * 128 + o];
        float w3 = W2t[(c4 * 4 + 3) * 128 + o];
#pragma unroll
        for (int r = 0; r < 4; ++r) {
            float4 f = *reinterpret_cast<const float4*>(&s_h1[(rh * 4 + r) * 128 + c4 * 4]);
            acc[r] += f.x * w0 + f.y * w1 + f.z * w2 + f.w * w3;
        }
    }
    float ps = 0.f;
#pragma unroll
    for (int r = 0; r < 4; ++r) ps += fmaxf(acc[r], 0.f);
    s_s[rh * 128 + o] = ps;
    __syncthreads();
    if (tid < 128)
        ssum[((size_t)n * 4 + qr) * 128 + tid] = s_s[tid] + s_s[128 + tid];
}

__global__ __launch_bounds__(256) void head_fc(const float* __restrict__ ssum,
                                               const float* __restrict__ HEAD,
                                               const float* __restrict__ bf1,
                                               const float* __restrict__ bf2,
                                               float* __restrict__ outp)
{
    __shared__ __align__(16) float s_sf[128];
    __shared__ __align__(16) float s_t1[256];

    const int n = blockIdx.x;
    const int tid = threadIdx.x;
    const float* F1t = HEAD + F_F1T;
    const float* F2t = HEAD + F_F2T;

    if (tid < 128) {
        const float* s0 = ssum + (size_t)n * 4 * 128 + tid;
        s_sf[tid] = (s0[0] + s0[128]) + (s0[256] + s0[384]);
    }
    __syncthreads();

    {
        float a = bf1[tid];
#pragma unroll 4
        for (int c4 = 0; c4 < 32; ++c4) {
            float4 f = *reinterpret_cast<const float4*>(&s_sf[c4 * 4]);
            a += f.x * F1t[(c4 * 4 + 0) * 256 + tid];
            a += f.y * F1t[(c4 * 4 + 1) * 256 + tid];
            a += f.z * F1t[(c4 * 4 + 2) * 256 + tid];
            a += f.w * F1t[(c4 * 4 + 3) * 256 + tid];
        }
        s_t1[tid] = fmaxf(a, 0.f);
    }
    __syncthreads();

    {
        float a = bf2[tid];
#pragma unroll 4
        for (int c4 = 0; c4 < 64; ++c4) {
            float4 f = *reinterpret_cast<const float4*>(&s_t1[c4 * 4]);
            a += f.x * F2t[(c4 * 4 + 0) * 256 + tid];
            a += f.y * F2t[(c4 * 4 + 1) * 256 + tid];
            a += f.z * F2t[(c4 * 4 + 2) * 256 + tid];
            a += f.w * F2t[(c4 * 4 + 3) * 256 + tid];
        }
        outp[(size_t)n * 256 + tid] = a;
    }
}

// ---------------------------------------------------------------------------
extern "C" void kernel_launch(void* const* d_in, const int* in_sizes, int n_in,
                              void* d_out, int out_size, void* d_ws, size_t ws_size,
                              hipStream_t stream)
{
    const int* pos = (const int*)d_in[0];
    const float* rt = (const float*)d_in[1];
    const float* emb = (const float*)d_in[2];
    const float* w1 = (const float*)d_in[3];
    const float* bc1 = (const float*)d_in[4];
    const float* w2 = (const float*)d_in[5];
    const float* bc2 = (const float*)d_in[6];
    const float* w3 = (const float*)d_in[7];
    const float* bc3 = (const float*)d_in[8];
    const float* wr1 = (const float*)d_in[9];
    const float* br1 = (const float*)d_in[10];
    const float* wr2 = (const float*)d_in[11];
    const float* br2 = (const float*)d_in[12];
    const float* wf1 = (const float*)d_in[13];
    const float* bf1 = (const float*)d_in[14];
    const float* wf2 = (const float*)d_in[15];
    const float* bf2 = (const float*)d_in[16];
    float* out = (float*)d_out;
    char* ws = (char*)d_ws;

    // merged prep: 225280 weight + 8192 imask + 32 room ids
    prep_all<<<913, 256, 0, stream>>>(w1, w2, w3, wr1, wr2, wf1, wf2, rt, pos, ws);

    const short* WALL = (const short*)(ws + B_W1F);
    const unsigned long long* RMASK = (const unsigned long long*)(ws + B_RAUX);
    const float* RINV = (const float*)(ws + B_RINV);
    const float* HEAD = (const float*)(ws + B_HEAD);
    float* FEAT = (float*)(ws + B_FEAT);
    unsigned* IMSK = (unsigned*)(ws + B_IMSK);
    float* SSUM = (float*)(ws + B_SSUM);

    fused_conv<<<dim3(RR, NB), 256, 0, stream>>>(IMSK, rt, emb, WALL,
                                                 bc1, bc2, bc3, pos, RMASK, FEAT);

    head_rooms<<<dim3(4, NB), 256, 0, stream>>>(FEAT, HEAD, RINV, br1, br2, SSUM);
    head_fc<<<NB, 256, 0, stream>>>(SSUM, HEAD, bf1, bf2, out);
}

// Round 16
// 268.501 us; speedup vs baseline: 3.2813x; 1.0139x over previous
//
#include <hip/hip_runtime.h>
#include <hip/hip_bf16.h>
#include <cstddef>

// Problem constants
#define NB 256   // batch
#define RR 32    // rooms
#define WW 8     // room width
#define HH 6     // room height
#define MXY 72   // map extent
#define EMB 6
#define CIN1 16  // 9 + 1 + 6

typedef __bf16 bf16x8 __attribute__((ext_vector_type(8)));
typedef float floatx4 __attribute__((ext_vector_type(4)));

// --- Workspace layout (byte offsets) ---------------------------------------
// Conv weights packed as 49 contiguous 4KB ksteps (round 16: the 14th conv1
// kstep was pure zero-padding — dropped; layout repacked so buffer parity
// alternates continuously across the conv1->conv2->conv3 chain):
//   conv1: ksteps 0..12 ; conv2: 13..30 ; conv3: 31..48
static const size_t B_W1F  = 0;
static const size_t B_W2F  = 53248;     // 13*4096
static const size_t B_W3F  = 126976;    // 31*4096  (end 200704)
static const size_t B_RAUX = 204800;    // room masks (32 u64)
static const size_t B_RINV = 205056;    // 1/room_size (32 f32)
static const size_t B_HEAD = 205312;    // fp32 head weights, 122880 floats
static const size_t F_WR1T = 0;         // (64,128)
static const size_t F_WR2T = 8192;      // (128,128)
static const size_t F_F1T  = 24576;     // (128,256)
static const size_t F_F2T  = 57344;     // (256,256)
static const size_t B_FEAT = 696832;    // (256,32,64) f32 = 2 MB
static const size_t B_IMSK = 2793984;   // (256,32) u32 intersect masks (32 KB)
static const size_t B_SSUM = 2826752;   // (256,4,128) f32 partial slots (512 KB)

__device__ inline short f2b(float f) {
    unsigned u = __builtin_bit_cast(unsigned, f);
    unsigned r = (u + 0x7fffu + ((u >> 16) & 1u)) >> 16;
    return (short)r;
}

// ---------------------------------------------------------------------------
// ONE merged prep kernel. Disjoint index ranges:
//   [0, 100352)          conv weights -> bf16 B-frag order (49 ksteps)
//   [100352, 223232)     head weight transposes (fp32)
//   [223232, 231424)     per-(sample,room) 32-bit intersect masks
//   [231424, 231456)     room footprint bitmasks + 1/room_size
// Fragment order: [kk][ntile][lane][j] ; virtual k = kk*32 + (lane>>4)*8 + j
// oc = ntile*16 + (lane&15).
// conv1: (tap,ci) natural. conv2/3: position cp -> channel (cp>>2)+(cp&3)*16
// (paired-channel layout Y1/Y2 are written in).
// ---------------------------------------------------------------------------
__global__ void prep_all(const float* __restrict__ w1, const float* __restrict__ w2,
                         const float* __restrict__ w3, const float* __restrict__ wr1,
                         const float* __restrict__ wr2, const float* __restrict__ wf1,
                         const float* __restrict__ wf2, const float* __restrict__ rt,
                         const int* __restrict__ pos, char* __restrict__ ws)
{
    short* W1F = (short*)(ws + B_W1F);
    short* W2F = (short*)(ws + B_W2F);
    short* W3F = (short*)(ws + B_W3F);
    float* HEAD = (float*)(ws + B_HEAD);

    int idx = blockIdx.x * 256 + threadIdx.x;
    if (idx < 26624) {  // conv1: 13 ksteps, CIN=16, taps 0..25 (25 zero-pad)
        int j = idx & 7, lane = (idx >> 3) & 63, nt = (idx >> 9) & 3, kk = idx >> 11;
        int k = kk * 32 + (lane >> 4) * 8 + j;
        int oc = nt * 16 + (lane & 15);
        int tap = k >> 4, ci = k & 15;
        float v = (tap < 25) ? w1[(oc * 16 + ci) * 25 + tap] : 0.f;
        W1F[idx] = f2b(v);
        return;
    }
    idx -= 26624;
    if (idx < 36864) {  // conv2: 18 ksteps, CIN=64, 9 taps, permuted ci
        int j = idx & 7, lane = (idx >> 3) & 63, nt = (idx >> 9) & 3, kk = idx >> 11;
        int k = kk * 32 + (lane >> 4) * 8 + j;
        int oc = nt * 16 + (lane & 15);
        int tap = k >> 6, cp = k & 63;
        int ci = (cp >> 2) + (cp & 3) * 16;
        W2F[idx] = f2b(w2[(oc * 64 + ci) * 9 + tap]);
        return;
    }
    idx -= 36864;
    if (idx < 36864) {  // conv3, permuted ci
        int j = idx & 7, lane = (idx >> 3) & 63, nt = (idx >> 9) & 3, kk = idx >> 11;
        int k = kk * 32 + (lane >> 4) * 8 + j;
        int oc = nt * 16 + (lane & 15);
        int tap = k >> 6, cp = k & 63;
        int ci = (cp >> 2) + (cp & 3) * 16;
        W3F[idx] = f2b(w3[(oc * 64 + ci) * 9 + tap]);
        return;
    }
    idx -= 36864;
    if (idx < 8192)  { int o = idx & 127, c = idx >> 7; HEAD[F_WR1T + idx] = wr1[o * 64 + c]; return; }
    idx -= 8192;
    if (idx < 16384) { int o = idx & 127, c = idx >> 7; HEAD[F_WR2T + idx] = wr2[o * 128 + c]; return; }
    idx -= 16384;
    if (idx < 32768) { int o = idx & 255, c = idx >> 8; HEAD[F_F1T + idx] = wf1[o * 128 + c]; return; }
    idx -= 32768;
    if (idx < 65536) { int o = idx & 255, c = idx >> 8; HEAD[F_F2T + idx] = wf2[o * 256 + c]; return; }
    idx -= 65536;
    if (idx < 8192) {  // intersect masks: rooms touching the 16x14 X halo tile
        const int n = idx >> 5, r0 = idx & 31;
        const int px0 = pos[(n * RR + r0) * 2 + 0];
        const int py0 = pos[(n * RR + r0) * 2 + 1];
        unsigned m = 0;
        for (int r = 0; r < RR; ++r) {
            int rpx = pos[(n * RR + r) * 2 + 0];
            int rpy = pos[(n * RR + r) * 2 + 1];
            if (rpx >= px0 - 11 && rpx <= px0 + 11 && rpy >= py0 - 9 && rpy <= py0 + 9)
                m |= 1u << r;
        }
        ((unsigned*)(ws + B_IMSK))[n * RR + r0] = m;
        return;
    }
    idx -= 8192;
    if (idx < RR) {  // room footprint bitmasks (48 bits) + 1/room_size
        unsigned long long m = 0ull;
        int cnt = 0;
        for (int j = 0; j < WW * HH; ++j)
            if (rt[idx * 9 * 48 + j] != 0.f) { m |= (1ull << j); ++cnt; }
        ((unsigned long long*)(ws + B_RAUX))[idx] = m;
        ((float*)(ws + B_RINV))[idx] = 1.f / (float)cnt;
    }
}

// ---------------------------------------------------------------------------
// ROUND-16 FUSED CONV: round-15's 1-kstep DMA pipeline (189us, 4 blk/CU) with
// two waste-removals:
//  * conv1 runs 13 ksteps (r14/15 silently computed a 14th all-zero kstep);
//    weights repacked to 49 contiguous ksteps, parity stays continuous.
//  * conv3 N-SPLIT: each of 4 waves owns one oc-tile (wave-uniform B read, 4
//    B-reads/kstep instead of 12), computes all 3 m-tiles, and owns a
//    disjoint 16-channel slice of s_feat (no LDS atomics, no zero-init).
//    Wave 3 no longer idles through 18 ksteps. (conv2 keeps M-split: its
//    paired-channel b64 epilogue requires waves to own pixels, not oc.)
// ---------------------------------------------------------------------------
__global__ __launch_bounds__(256, 4) void fused_conv(
    const unsigned* __restrict__ imask, const float* __restrict__ rt,
    const float* __restrict__ emb, const short* __restrict__ wAll,
    const float* __restrict__ bc1, const float* __restrict__ bc2,
    const float* __restrict__ bc3, const int* __restrict__ pos,
    const unsigned long long* __restrict__ rmask, float* __restrict__ feat)
{
    __shared__ __align__(16) short s_Y1[120 * 72];   // 17280 B, paired-channel
    __shared__ __align__(16) short s_u[80 * 72];     // X[224][24] then Y2[80][72]
    __shared__ __align__(16) short s_B[2][2048];     // 1-kstep weight dbuf (8KB)
    __shared__ float s_feat[64];

    const int tid = threadIdx.x;
    const int lane = tid & 63;
    const int wv = tid >> 6;
    const int ml = lane & 15;
    const int q = lane >> 4;
    const int room = blockIdx.x;
    const int n = blockIdx.y;

    const int px = pos[(n * RR + room) * 2 + 0];
    const int py = pos[(n * RR + room) * 2 + 1];

    const char* wB = (const char*)wAll;
    // DMA one 4KB kstep into its parity buffer (1KB per wave)
    auto dma = [&](int k) {
        const char* src = wB + (size_t)k * 4096 + wv * 1024 + lane * 16;
        __builtin_amdgcn_global_load_lds(
            (const __attribute__((address_space(1))) unsigned int*)src,
            (__attribute__((address_space(3))) unsigned int*)&s_B[k & 1][wv * 512],
            16, 0, 0);
    };

    dma(0);

    // ---- build X tile in-kernel: threads 0..223, one 16-channel pixel ----
    {
        const unsigned mk0 = imask[n * RR + room];  // uniform
        if (tid < 224) {
            const int row = tid / 14, col = tid - (tid / 14) * 14;
            const int gx = px - 4 + row, gy = py - 4 + col;
            float a[16];
#pragma unroll
            for (int c = 0; c < 16; ++c) a[c] = 0.f;
            a[9] = ((unsigned)gx < (unsigned)MXY && (unsigned)gy < (unsigned)MXY) ? 1.f : 0.f;

            unsigned mm = mk0;
            while (mm) {
                const int r = __builtin_ctz(mm);
                mm &= mm - 1;
                const int rpx = pos[(n * RR + r) * 2 + 0];  // uniform -> s_load
                const int rpy = pos[(n * RR + r) * 2 + 1];
                const int w = gx - rpx, h = gy - rpy;
                if ((unsigned)w < (unsigned)WW && (unsigned)h < (unsigned)HH) {
                    const int j = w * HH + h;
                    const float* rr = rt + r * 9 * 48;
#pragma unroll
                    for (int c = 0; c < 9; ++c) a[c] += rr[c * 48 + j];
                    const float mv = rr[j];  // channel 0 = room_map
#pragma unroll
                    for (int e = 0; e < EMB; ++e) a[10 + e] += emb[r * EMB + e] * mv;
                }
            }
            short o[16];
#pragma unroll
            for (int c = 0; c < 16; ++c) o[c] = f2b(a[c]);
            *reinterpret_cast<uint4*>(&s_u[tid * 24 + 0]) = *reinterpret_cast<uint4*>(o);
            *reinterpret_cast<uint4*>(&s_u[tid * 24 + 8]) = *reinterpret_cast<uint4*>(o + 8);
        }
    }
    __syncthreads();  // X staged, weight kstep 0 resident

    // ================= conv1: 5x5, X(16ch) -> Y1 12x10x64 =================
    {
        int prow[2], pcol[2];
#pragma unroll
        for (int i = 0; i < 2; ++i) {
            int p = wv * 32 + i * 16 + ml;
            if (p > 119) p = 119;  // pad px: duplicate compute, discarded
            prow[i] = p / 10; pcol[i] = p - prow[i] * 10;
        }
        floatx4 acc1[2][4] = {};

#pragma unroll
        for (int k = 0; k < 13; ++k) {  // ksteps 0..12 (taps 0..25, 25=zero)
            dma(k + 1);                  // k=12 prefetches conv2 kstep 13
            const short* sb = s_B[k & 1];
            bf16x8 Bf[4];
#pragma unroll
            for (int j2 = 0; j2 < 4; ++j2)
                Bf[j2] = *reinterpret_cast<const bf16x8*>(&sb[(j2 * 64 + lane) * 8]);
            int tap = k * 2 + (q >> 1);
            if (tap > 24) tap = 24;  // k-slots past tap24 have zero weights
            const int chb = (q & 1) * 8;
            const int dx = tap / 5, dy = tap - (tap / 5) * 5;
            __builtin_amdgcn_s_setprio(1);
#pragma unroll
            for (int i = 0; i < 2; ++i) {
                bf16x8 A = *reinterpret_cast<const bf16x8*>(
                    &s_u[((prow[i] + dx) * 14 + (pcol[i] + dy)) * 24 + chb]);
#pragma unroll
                for (int j2 = 0; j2 < 4; ++j2)
                    acc1[i][j2] = __builtin_amdgcn_mfma_f32_16x16x32_bf16(
                        A, Bf[j2], acc1[i][j2], 0, 0, 0);
            }
            __builtin_amdgcn_s_setprio(0);
            if (k == 12) {  // epilogue: bias+relu, b64 paired-channel stores
                float b4[4];
#pragma unroll
                for (int j2 = 0; j2 < 4; ++j2) b4[j2] = bc1[j2 * 16 + ml];
#pragma unroll
                for (int i = 0; i < 2; ++i)
#pragma unroll
                    for (int r = 0; r < 4; ++r) {
                        int p = wv * 32 + i * 16 + q * 4 + r;
                        if (p < 120) {
                            unsigned lo = (unsigned)(unsigned short)f2b(fmaxf(acc1[i][0][r] + b4[0], 0.f))
                                        | ((unsigned)(unsigned short)f2b(fmaxf(acc1[i][1][r] + b4[1], 0.f)) << 16);
                            unsigned hi = (unsigned)(unsigned short)f2b(fmaxf(acc1[i][2][r] + b4[2], 0.f))
                                        | ((unsigned)(unsigned short)f2b(fmaxf(acc1[i][3][r] + b4[3], 0.f)) << 16);
                            *reinterpret_cast<uint2*>(&s_Y1[p * 72 + ml * 4]) = make_uint2(lo, hi);
                        }
                    }
            }
            __syncthreads();
        }
    }

    // ===== conv2: 3x3, Y1 -> Y2 10x8x64 (tiles 0-3 owned, tile 4 n-split) ==
    {
        int prowA, pcolA, prowB, pcolB;
        {
            int p0 = wv * 16 + ml; prowA = p0 >> 3; pcolA = p0 & 7;
            int p1 = 64 + ml;      prowB = p1 >> 3; pcolB = p1 & 7;
        }
        floatx4 acc2[4] = {};
        floatx4 acc2s = {};

#pragma unroll
        for (int k = 13; k < 31; ++k) {  // global ksteps 13..30
            dma(k + 1);                   // k=30 prefetches conv3 kstep 31
            const short* sb = s_B[k & 1];
            const int kk = k - 13;
            bf16x8 Bf[4];
#pragma unroll
            for (int j2 = 0; j2 < 4; ++j2)
                Bf[j2] = *reinterpret_cast<const bf16x8*>(&sb[(j2 * 64 + lane) * 8]);
            // 5th-tile B frag: wave-uniform LDS base (rule #20 safe)
            bf16x8 B4 = *reinterpret_cast<const bf16x8*>(&sb[(wv * 64 + lane) * 8]);
            const int tap = kk >> 1;
            const int chb = (kk & 1) * 32 + q * 8;
            const int dx = tap / 3, dy = tap - (tap / 3) * 3;
            bf16x8 A0 = *reinterpret_cast<const bf16x8*>(
                &s_Y1[((prowA + dx) * 10 + (pcolA + dy)) * 72 + chb]);
            bf16x8 A4 = *reinterpret_cast<const bf16x8*>(
                &s_Y1[((prowB + dx) * 10 + (pcolB + dy)) * 72 + chb]);
            __builtin_amdgcn_s_setprio(1);
#pragma unroll
            for (int j2 = 0; j2 < 4; ++j2)
                acc2[j2] = __builtin_amdgcn_mfma_f32_16x16x32_bf16(A0, Bf[j2], acc2[j2], 0, 0, 0);
            acc2s = __builtin_amdgcn_mfma_f32_16x16x32_bf16(A4, B4, acc2s, 0, 0, 0);
            __builtin_amdgcn_s_setprio(0);
            if (k == 30) {  // epilogue into s_u (X is dead)
                float b4[4];
#pragma unroll
                for (int j2 = 0; j2 < 4; ++j2) b4[j2] = bc2[j2 * 16 + ml];
#pragma unroll
                for (int r = 0; r < 4; ++r) {
                    int p = wv * 16 + q * 4 + r;
                    unsigned lo = (unsigned)(unsigned short)f2b(fmaxf(acc2[0][r] + b4[0], 0.f))
                                | ((unsigned)(unsigned short)f2b(fmaxf(acc2[1][r] + b4[1], 0.f)) << 16);
                    unsigned hi = (unsigned)(unsigned short)f2b(fmaxf(acc2[2][r] + b4[2], 0.f))
                                | ((unsigned)(unsigned short)f2b(fmaxf(acc2[3][r] + b4[3], 0.f)) << 16);
                    *reinterpret_cast<uint2*>(&s_u[p * 72 + ml * 4]) = make_uint2(lo, hi);
                }
                float bt = bc2[wv * 16 + ml];
#pragma unroll
                for (int r = 0; r < 4; ++r) {
                    int p = 64 + q * 4 + r;
                    s_u[p * 72 + ml * 4 + wv] = f2b(fmaxf(acc2s[r] + bt, 0.f));
                }
            }
            __syncthreads();
        }
    }

    // == conv3: 3x3, Y2 -> 8x6 masked room-sum. N-SPLIT: wave wv owns ==
    // == oc-tile wv (16 channels), computes all 3 m-tiles (48 px).     ==
    {
        int prow3[3], pcol3[3];
#pragma unroll
        for (int i = 0; i < 3; ++i) {
            int p = i * 16 + ml;
            prow3[i] = p / 6; pcol3[i] = p - (p / 6) * 6;
        }
        floatx4 acc3[3] = {};

#pragma unroll
        for (int k = 31; k < 49; ++k) {  // global ksteps 31..48
            if (k + 1 < 49) dma(k + 1);
            const short* sb = s_B[k & 1];
            const int kk = k - 31;
            // own oc-tile's B frag: wave-uniform LDS base (rule #20 safe)
            bf16x8 Bf = *reinterpret_cast<const bf16x8*>(&sb[(wv * 64 + lane) * 8]);
            const int tap = kk >> 1;
            const int chb = (kk & 1) * 32 + q * 8;
            const int dx = tap / 3, dy = tap - (tap / 3) * 3;
            __builtin_amdgcn_s_setprio(1);
#pragma unroll
            for (int i = 0; i < 3; ++i) {
                bf16x8 A = *reinterpret_cast<const bf16x8*>(
                    &s_u[((prow3[i] + dx) * 8 + (pcol3[i] + dy)) * 72 + chb]);
                acc3[i] = __builtin_amdgcn_mfma_f32_16x16x32_bf16(A, Bf, acc3[i], 0, 0, 0);
            }
            __builtin_amdgcn_s_setprio(0);
            if (k == 48) {  // masked reduce; wave owns channels wv*16..+15
                const float bt = bc3[wv * 16 + ml];
                float part = 0.f;
                const unsigned long long mk = rmask[room];
#pragma unroll
                for (int i = 0; i < 3; ++i)
#pragma unroll
                    for (int r = 0; r < 4; ++r) {
                        int p = i * 16 + q * 4 + r;  // == w*6+h == mask bit
                        if ((mk >> p) & 1ull)
                            part += fmaxf(acc3[i][r] + bt, 0.f);
                    }
                part += __shfl_xor(part, 16);
                part += __shfl_xor(part, 32);
                if (q == 0) s_feat[wv * 16 + ml] = part;  // disjoint slices
            }
            __syncthreads();
        }
    }

    if (tid < 64)
        feat[((size_t)n * RR + room) * 64 + tid] = s_feat[tid];
}

// ---------------------------------------------------------------------------
// Head split (round-13, proven): head_rooms = 4 blocks/sample, 8 rooms each
// (amortizes the 96KB head-weight read; 1-room fusion was L2-bound, r12).
// Partial room-sums to PRIVATE slots (no atomics/zeroing); head_fc sums 4.
// ---------------------------------------------------------------------------
__global__ __launch_bounds__(256) void head_rooms(const float* __restrict__ feat,
                                                  const float* __restrict__ HEAD,
                                                  const float* __restrict__ rinv,
                                                  const float* __restrict__ b1,
                                                  const float* __restrict__ b2,
                                                  float* __restrict__ ssum)
{
    __shared__ __align__(16) float s_feat[8 * 64];
    __shared__ __align__(16) float s_h1[8 * 128];
    __shared__ __align__(16) float s_s[2 * 128];

    const int qr = blockIdx.x;   // 0..3 -> rooms qr*8 .. qr*8+7
    const int n = blockIdx.y;
    const int tid = threadIdx.x;
    const float* W1t = HEAD + F_WR1T;
    const float* W2t = HEAD + F_WR2T;

    for (int i = tid; i < 8 * 64; i += 256)
        s_feat[i] = feat[(size_t)n * RR * 64 + qr * 512 + i] * rinv[qr * 8 + (i >> 6)];
    __syncthreads();

    const int o = tid & 127;
    const int rh = tid >> 7;     // rooms rh*4 .. rh*4+3 (local)

    float acc[4];
#pragma unroll
    for (int r = 0; r < 4; ++r) acc[r] = b1[o];
    for (int c4 = 0; c4 < 16; ++c4) {
        float w0 = W1t[(c4 * 4 + 0) * 128 + o];
        float w1 = W1t[(c4 * 4 + 1) * 128 + o];
        float w2 = W1t[(c4 * 4 + 2) * 128 + o];
        float w3 = W1t[(c4 * 4 + 3) * 128 + o];
#pragma unroll
        for (int r = 0; r < 4; ++r) {
            float4 f = *reinterpret_cast<const float4*>(&s_feat[(rh * 4 + r) * 64 + c4 * 4]);
            acc[r] += f.x * w0 + f.y * w1 + f.z * w2 + f.w * w3;
        }
    }
#pragma unroll
    for (int r = 0; r < 4; ++r) s_h1[(rh * 4 + r) * 128 + o] = fmaxf(acc[r], 0.f);
    __syncthreads();

#pragma unroll
    for (int r = 0; r < 4; ++r) acc[r] = b2[o];
    for (int c4 = 0; c4 < 32; ++c4) {
        float w0 = W2t[(c4 * 4 + 0) * 128 + o];
        float w1 = W2t[(c4 * 4 + 1) * 128 + o];
        float w2 = W2t[(c4 * 4 + 2) * 128 + o];
        float w3 = W2t[(c4 * 4 + 3) * 128 + o];
#pragma unroll
        for (int r = 0; r < 4; ++r) {
            float4 f = *reinterpret_cast<const float4*>(&s_h1[(rh * 4 + r) * 128 + c4 * 4]);
            acc[r] += f.x * w0 + f.y * w1 + f.z * w2 + f.w * w3;
        }
    }
    float ps = 0.f;
#pragma unroll
    for (int r = 0; r < 4; ++r) ps += fmaxf(acc[r], 0.f);
    s_s[rh * 128 + o] = ps;
    __syncthreads();
    if (tid < 128)
        ssum[((size_t)n * 4 + qr) * 128 + tid] = s_s[tid] + s_s[128 + tid];
}

__global__ __launch_bounds__(256) void head_fc(const float* __restrict__ ssum,
                                               const float* __restrict__ HEAD,
                                               const float* __restrict__ bf1,
                                               const float* __restrict__ bf2,
                                               float* __restrict__ outp)
{
    __shared__ __align__(16) float s_sf[128];
    __shared__ __align__(16) float s_t1[256];

    const int n = blockIdx.x;
    const int tid = threadIdx.x;
    const float* F1t = HEAD + F_F1T;
    const float* F2t = HEAD + F_F2T;

    if (tid < 128) {
        const float* s0 = ssum + (size_t)n * 4 * 128 + tid;
        s_sf[tid] = (s0[0] + s0[128]) + (s0[256] + s0[384]);
    }
    __syncthreads();

    {
        float a = bf1[tid];
#pragma unroll 4
        for (int c4 = 0; c4 < 32; ++c4) {
            float4 f = *reinterpret_cast<const float4*>(&s_sf[c4 * 4]);
            a += f.x * F1t[(c4 * 4 + 0) * 256 + tid];
            a += f.y * F1t[(c4 * 4 + 1) * 256 + tid];
            a += f.z * F1t[(c4 * 4 + 2) * 256 + tid];
            a += f.w * F1t[(c4 * 4 + 3) * 256 + tid];
        }
        s_t1[tid] = fmaxf(a, 0.f);
    }
    __syncthreads();

    {
        float a = bf2[tid];
#pragma unroll 4
        for (int c4 = 0; c4 < 64; ++c4) {
            float4 f = *reinterpret_cast<const float4*>(&s_t1[c4 * 4]);
            a += f.x * F2t[(c4 * 4 + 0) * 256 + tid];
            a += f.y * F2t[(c4 * 4 + 1) * 256 + tid];
            a += f.z * F2t[(c4 * 4 + 2) * 256 + tid];
            a += f.w * F2t[(c4 * 4 + 3) * 256 + tid];
        }
        outp[(size_t)n * 256 + tid] = a;
    }
}

// ---------------------------------------------------------------------------
extern "C" void kernel_launch(void* const* d_in, const int* in_sizes, int n_in,
                              void* d_out, int out_size, void* d_ws, size_t ws_size,
                              hipStream_t stream)
{
    const int* pos = (const int*)d_in[0];
    const float* rt = (const float*)d_in[1];
    const float* emb = (const float*)d_in[2];
    const float* w1 = (const float*)d_in[3];
    const float* bc1 = (const float*)d_in[4];
    const float* w2 = (const float*)d_in[5];
    const float* bc2 = (const float*)d_in[6];
    const float* w3 = (const float*)d_in[7];
    const float* bc3 = (const float*)d_in[8];
    const float* wr1 = (const float*)d_in[9];
    const float* br1 = (const float*)d_in[10];
    const float* wr2 = (const float*)d_in[11];
    const float* br2 = (const float*)d_in[12];
    const float* wf1 = (const float*)d_in[13];
    const float* bf1 = (const float*)d_in[14];
    const float* wf2 = (const float*)d_in[15];
    const float* bf2 = (const float*)d_in[16];
    float* out = (float*)d_out;
    char* ws = (char*)d_ws;

    // merged prep: 100352 weight + 122880 head + 8192 imask + 32 room ids
    prep_all<<<905, 256, 0, stream>>>(w1, w2, w3, wr1, wr2, wf1, wf2, rt, pos, ws);

    const short* WALL = (const short*)(ws + B_W1F);
    const unsigned long long* RMASK = (const unsigned long long*)(ws + B_RAUX);
    const float* RINV = (const float*)(ws + B_RINV);
    const float* HEAD = (const float*)(ws + B_HEAD);
    float* FEAT = (float*)(ws + B_FEAT);
    unsigned* IMSK = (unsigned*)(ws + B_IMSK);
    float* SSUM = (float*)(ws + B_SSUM);

    fused_conv<<<dim3(RR, NB), 256, 0, stream>>>(IMSK, rt, emb, WALL,
                                                 bc1, bc2, bc3, pos, RMASK, FEAT);

    head_rooms<<<dim3(4, NB), 256, 0, stream>>>(FEAT, HEAD, RINV, br1, br2, SSUM);
    head_fc<<<NB, 256, 0, stream>>>(SSUM, HEAD, bf1, bf2, out);
}